// Round 14
// baseline (189.766 us; speedup 1.0000x reference)
//
#include <hip/hip_runtime.h>
#include <hip/hip_fp16.h>

constexpr int F  = 64;   // IN_FEATS == ATT_HEADS*H_FEATS
constexpr int HEADS = 4;
constexpr int K_SLOT = 64;   // per-dst slot capacity (deg>64 -> overflow list)

// ---------------------------------------------------------------------------
// Tier-2 sign fallback, STREAMING form: literal fp32 192-term sequential FMA
// in the reference's e_feat section order (bit-identical to the buffered
// version: same values, same order). ~12 VGPRs, used for ~200 edges total.
// ---------------------------------------------------------------------------
__device__ __noinline__ float tier2_sign_stream(
    const float* __restrict__ tfeat, const float* __restrict__ W_f,
    int s, int d, float bf)
{
    const float4* ts = reinterpret_cast<const float4*>(tfeat + (size_t)s * F);
    const float4* td = reinterpret_cast<const float4*>(tfeat + (size_t)d * F);
    const float4* wf = reinterpret_cast<const float4*>(W_f);
    float acc = 0.f;
#pragma unroll
    for (int i = 0; i < 16; i++) {
        float4 a = ts[i], w = wf[i];
        acc = fmaf(a.x, w.x, acc); acc = fmaf(a.y, w.y, acc);
        acc = fmaf(a.z, w.z, acc); acc = fmaf(a.w, w.w, acc);
    }
#pragma unroll
    for (int i = 0; i < 16; i++) {
        float4 a = td[i], w = wf[16 + i];
        acc = fmaf(a.x, w.x, acc); acc = fmaf(a.y, w.y, acc);
        acc = fmaf(a.z, w.z, acc); acc = fmaf(a.w, w.w, acc);
    }
#pragma unroll
    for (int i = 0; i < 16; i++) {
        float4 a = ts[i], b = td[i], w = wf[32 + i];
        acc = fmaf(a.x - b.x, w.x, acc); acc = fmaf(a.y - b.y, w.y, acc);
        acc = fmaf(a.z - b.z, w.z, acc); acc = fmaf(a.w - b.w, w.w, acc);
    }
    float sp = acc + bf;
    return (sp > 0.f) ? 1.f : (sp < 0.f ? -1.f : 0.f);
}

// ---------------------------------------------------------------------------
// K1 fused: blocks [0,nb): W_d path (tfeat fp32 BLAS-order, u/v fp32).
//           blocks [nb,2nb): W_w path (hp fp16, a_src/a_dst fp32).
//           blocks [2nb,...): edge path — pos=atomicAdd(cnt[d]);
//               slot[d*64+pos]=src. Minimal chain; GEMMs hide atomic latency.
// No intra-kernel dependencies (sign moved to K2-gather).
// ---------------------------------------------------------------------------
__global__ __launch_bounds__(256) void fused_kernel(
    const float* __restrict__ h,
    const float* __restrict__ W_w, const float* __restrict__ b_w,
    const float* __restrict__ W_a,
    const float* __restrict__ W_d, const float* __restrict__ b_d,
    const float* __restrict__ W_f,
    float* __restrict__ tfeat, __half* __restrict__ hp,
    float* __restrict__ u_arr, float* __restrict__ v_arr,
    float* __restrict__ a_src, float* __restrict__ a_dst,
    const int* __restrict__ src_idx, const int* __restrict__ dst_idx,
    unsigned* __restrict__ cnt, unsigned* __restrict__ slot,
    unsigned* __restrict__ of_list, unsigned* __restrict__ of_cnt,
    int N, int E, int nb, unsigned of_cap)
{
    int tid = threadIdx.x;

    if (blockIdx.x >= 2 * nb) {
        // ---- edge path: bare count + slot scatter (2 edges/thread) ----
        int eb = blockIdx.x - 2 * nb;
        int e0 = eb * 512 + tid;
        int e1 = e0 + 256;
        bool ok0 = e0 < E, ok1 = e1 < E;

        int s0 = 0, d0 = 0, s1 = 0, d1 = 0;
        if (ok0) { s0 = src_idx[e0]; d0 = dst_idx[e0]; }
        if (ok1) { s1 = src_idx[e1]; d1 = dst_idx[e1]; }

        unsigned p0 = ok0 ? atomicAdd(&cnt[d0], 1u) : 0u;
        unsigned p1 = ok1 ? atomicAdd(&cnt[d1], 1u) : 0u;

        if (ok0) {
            if (p0 < (unsigned)K_SLOT) slot[(size_t)d0 * K_SLOT + p0] = (unsigned)s0;
            else {
                unsigned oi = atomicAdd(of_cnt, 1u);
                if (oi < of_cap) { of_list[2 * oi] = (unsigned)d0; of_list[2 * oi + 1] = (unsigned)s0; }
            }
        }
        if (ok1) {
            if (p1 < (unsigned)K_SLOT) slot[(size_t)d1 * K_SLOT + p1] = (unsigned)s1;
            else {
                unsigned oi = atomicAdd(of_cnt, 1u);
                if (oi < of_cap) { of_list[2 * oi] = (unsigned)d1; of_list[2 * oi + 1] = (unsigned)s1; }
            }
        }
        return;
    }

    // ---- node GEMM paths ----
    __shared__ float sWT[F * F];     // [j][k] transposed
    __shared__ float sb[F];
    __shared__ double swfA[F], swfB[F];
    __shared__ float sWa[32];

    bool isW = blockIdx.x >= nb;
    const float* Wsrc = isW ? W_w : W_d;
    for (int i = tid; i < F * F; i += 256) {
        int k = i >> 6, j = i & 63;
        sWT[j * F + k] = Wsrc[i];
    }
    if (tid < F) sb[tid] = isW ? b_w[tid] : b_d[tid];
    if (!isW && tid < F) {
        swfA[tid] = (double)W_f[tid] + (double)W_f[2 * F + tid];
        swfB[tid] = (double)W_f[F + tid] - (double)W_f[2 * F + tid];
    }
    if (isW && tid < 32) sWa[tid] = W_a[tid];
    __syncthreads();

    int blk = isW ? (blockIdx.x - nb) : blockIdx.x;
    int n = blk * 256 + tid;
    if (n >= N) return;

    float4 hv[16];
    const float4* h4 = reinterpret_cast<const float4*>(h + (size_t)n * F);
#pragma unroll
    for (int i = 0; i < 16; i++) hv[i] = h4[i];

    if (!isW) {
        // ---- W_d path: tfeat row + u,v ----
        double u = 0.0, v = 0.0;
        float4 tq;
        float4* trow = reinterpret_cast<float4*>(tfeat + (size_t)n * F);
#pragma unroll 4
        for (int j = 0; j < F; j++) {
            const float4* row = reinterpret_cast<const float4*>(&sWT[j * F]);
            float t = 0.f;
#pragma unroll
            for (int kk = 0; kk < 16; kk++) {
                float4 w = row[kk];
                float4 x = hv[kk];
                t = fmaf(x.x, w.x, t);
                t = fmaf(x.y, w.y, t);
                t = fmaf(x.z, w.z, t);
                t = fmaf(x.w, w.w, t);
            }
            t = t + sb[j];
            u = fma((double)t, swfA[j], u);
            v = fma((double)t, swfB[j], v);
            if ((j & 3) == 0) tq.x = t;
            else if ((j & 3) == 1) tq.y = t;
            else if ((j & 3) == 2) tq.z = t;
            else { tq.w = t; trow[j >> 2] = tq; }
        }
        u_arr[n] = (float)u;
        v_arr[n] = (float)v;
    } else {
        // ---- W_w path: hp row (fp16) + a_src,a_dst per head ----
        __half2* prow = reinterpret_cast<__half2*>(hp + (size_t)n * F);
#pragma unroll
        for (int qh = 0; qh < 4; qh++) {
            float asq = 0.f, adq = 0.f;
            float pprev = 0.f;
#pragma unroll 4
            for (int jj = 0; jj < 16; jj++) {
                int j = qh * 16 + jj;
                const float4* row = reinterpret_cast<const float4*>(&sWT[j * F]);
                float p = 0.f;
#pragma unroll
                for (int kk = 0; kk < 16; kk++) {
                    float4 w = row[kk];
                    float4 x = hv[kk];
                    p = fmaf(x.x, w.x, p);
                    p = fmaf(x.y, w.y, p);
                    p = fmaf(x.z, w.z, p);
                    p = fmaf(x.w, w.w, p);
                }
                p = p + sb[j];
                asq = fmaf(p, sWa[jj], asq);
                adq = fmaf(p, sWa[16 + jj], adq);
                if ((jj & 1) == 0) pprev = p;
                else prow[j >> 1] = __floats2half2_rn(pprev, p);
            }
            a_src[n * HEADS + qh] = asq;
            a_dst[n * HEADS + qh] = adq;
        }
    }
}

// ---------------------------------------------------------------------------
// K2: one wave per dst. Phase A: lane<deg reads slot -> s; computes sign
// (fp32 margin u[s]+v[d]+bf; rare tier2 streaming fallback), 4 exp weights
// once per edge; stash {sgn*ex4, s} in LDS; esum partial; butterfly.
// Phase B: 8-way ILP LDS-fed fp16 hp gather; one normalize; one 256B store.
// Slow path (deg>64): recompute over clamped slots + of_list.
// ---------------------------------------------------------------------------
__global__ __launch_bounds__(256) void dst_gather_kernel(
    const unsigned* __restrict__ cnt,
    const unsigned* __restrict__ slot,
    const unsigned* __restrict__ of_list, const unsigned* __restrict__ of_cnt,
    const float* __restrict__ u_arr, const float* __restrict__ v_arr,
    const float* __restrict__ tfeat, const float* __restrict__ W_f,
    const float* __restrict__ b_f,
    const float* __restrict__ a_src, const float* __restrict__ a_dst,
    const float* __restrict__ b_a,
    const __half* __restrict__ hp,
    float* __restrict__ out, int N, unsigned of_cap)
{
    __shared__ float sw[4][K_SLOT * 4];     // [wave][slot*4+head] = sgn*ex
    __shared__ unsigned ssrc[4][K_SLOT];    // [wave][slot] = src index

    int tid = threadIdx.x;
    int wslot = tid >> 6;
    int lane = tid & 63;
    int q = lane >> 4;
    int d = (blockIdx.x * 256 + tid) >> 6;
    bool valid = d < N;

    float ba = b_a[0], bf = b_f[0];
    float4 ad4 = make_float4(0.f, 0.f, 0.f, 0.f);
    unsigned deg = 0;
    float vd = 0.f;
    if (valid) {
        deg = cnt[d];
        ad4 = *reinterpret_cast<const float4*>(a_dst + (size_t)d * HEADS);
        vd = v_arr[d];
    }
    float adq = (q == 0) ? ad4.x : (q == 1) ? ad4.y : (q == 2) ? ad4.z : ad4.w;
    unsigned mdeg = min(deg, (unsigned)K_SLOT);
    bool fast = valid && (deg <= (unsigned)K_SLOT);

    // Phase A: one slot per lane
    float4 p = make_float4(0.f, 0.f, 0.f, 0.f);
    if (valid && lane < (int)mdeg) {
        unsigned s = slot[(size_t)d * K_SLOT + lane];
        float us = u_arr[s];
        float m = us + vd + bf;
        float sgn = (fabsf(m) >= 1e-4f) ? ((m > 0.f) ? 1.f : -1.f)
                                        : tier2_sign_stream(tfeat, W_f, (int)s, d, bf);
        float4 as4 = *reinterpret_cast<const float4*>(a_src + (size_t)s * HEADS);
        float ap0 = fmaf(sgn, as4.x, ad4.x) + ba;
        float ap1 = fmaf(sgn, as4.y, ad4.y) + ba;
        float ap2 = fmaf(sgn, as4.z, ad4.z) + ba;
        float ap3 = fmaf(sgn, as4.w, ad4.w) + ba;
        float e0 = expf(ap0 > 0.f ? ap0 : 0.01f * ap0);
        float e1 = expf(ap1 > 0.f ? ap1 : 0.01f * ap1);
        float e2 = expf(ap2 > 0.f ? ap2 : 0.01f * ap2);
        float e3 = expf(ap3 > 0.f ? ap3 : 0.01f * ap3);
        p = make_float4(e0, e1, e2, e3);
        *reinterpret_cast<float4*>(&sw[wslot][lane * 4]) =
            make_float4(sgn * e0, sgn * e1, sgn * e2, sgn * e3);
        ssrc[wslot][lane] = s;
    }
    if (valid && !fast) {
        // overflow esum contributions from of_list (deg>64; effectively never)
        unsigned on = min(*of_cnt, of_cap);
        for (unsigned i = lane; i < on; i += 64) {
            if (of_list[2 * i] == (unsigned)d) {
                unsigned s = of_list[2 * i + 1];
                float us = u_arr[s];
                float m = us + vd + bf;
                float sgn = (fabsf(m) >= 1e-4f) ? ((m > 0.f) ? 1.f : -1.f)
                                                : tier2_sign_stream(tfeat, W_f, (int)s, d, bf);
                float4 as4 = *reinterpret_cast<const float4*>(a_src + (size_t)s * HEADS);
                float ap0 = fmaf(sgn, as4.x, ad4.x) + ba;
                float ap1 = fmaf(sgn, as4.y, ad4.y) + ba;
                float ap2 = fmaf(sgn, as4.z, ad4.z) + ba;
                float ap3 = fmaf(sgn, as4.w, ad4.w) + ba;
                p.x += expf(ap0 > 0.f ? ap0 : 0.01f * ap0);
                p.y += expf(ap1 > 0.f ? ap1 : 0.01f * ap1);
                p.z += expf(ap2 > 0.f ? ap2 : 0.01f * ap2);
                p.w += expf(ap3 > 0.f ? ap3 : 0.01f * ap3);
            }
        }
    }
    __syncthreads();

#pragma unroll
    for (int off = 32; off >= 1; off >>= 1) {
        p.x += __shfl_xor(p.x, off);
        p.y += __shfl_xor(p.y, off);
        p.z += __shfl_xor(p.z, off);
        p.w += __shfl_xor(p.w, off);
    }
    if (!valid) return;

    float esq = (q == 0) ? p.x : (q == 1) ? p.y : (q == 2) ? p.z : p.w;
    float rinv = (deg > 0) ? (1.0f / esq) : 0.f;

    const float* swb = &sw[wslot][0];
    const unsigned* ssb = &ssrc[wslot][0];

    // Phase B: 8-way ILP over LDS-cached {weight, src}
    float a0 = 0.f, a1 = 0.f, a2 = 0.f, a3 = 0.f;
    unsigned t0 = 0;
    for (; t0 + 8 <= mdeg; t0 += 8) {
        float w0 = swb[(t0 + 0) * 4 + q], w1 = swb[(t0 + 1) * 4 + q];
        float w2 = swb[(t0 + 2) * 4 + q], w3 = swb[(t0 + 3) * 4 + q];
        float w4 = swb[(t0 + 4) * 4 + q], w5 = swb[(t0 + 5) * 4 + q];
        float w6 = swb[(t0 + 6) * 4 + q], w7 = swb[(t0 + 7) * 4 + q];
        unsigned s0 = ssb[t0 + 0], s1 = ssb[t0 + 1];
        unsigned s2 = ssb[t0 + 2], s3 = ssb[t0 + 3];
        unsigned s4 = ssb[t0 + 4], s5 = ssb[t0 + 5];
        unsigned s6 = ssb[t0 + 6], s7 = ssb[t0 + 7];
        float h0 = __half2float(hp[((size_t)s0 << 6) | (unsigned)lane]);
        float h1 = __half2float(hp[((size_t)s1 << 6) | (unsigned)lane]);
        float h2 = __half2float(hp[((size_t)s2 << 6) | (unsigned)lane]);
        float h3 = __half2float(hp[((size_t)s3 << 6) | (unsigned)lane]);
        float h4 = __half2float(hp[((size_t)s4 << 6) | (unsigned)lane]);
        float h5 = __half2float(hp[((size_t)s5 << 6) | (unsigned)lane]);
        float h6 = __half2float(hp[((size_t)s6 << 6) | (unsigned)lane]);
        float h7 = __half2float(hp[((size_t)s7 << 6) | (unsigned)lane]);
        a0 = fmaf(w0, h0, a0); a1 = fmaf(w1, h1, a1);
        a2 = fmaf(w2, h2, a2); a3 = fmaf(w3, h3, a3);
        a0 = fmaf(w4, h4, a0); a1 = fmaf(w5, h5, a1);
        a2 = fmaf(w6, h6, a2); a3 = fmaf(w7, h7, a3);
    }
    for (; t0 < mdeg; t0++) {
        float w = swb[t0 * 4 + q];
        unsigned s = ssb[t0];
        a0 = fmaf(w, __half2float(hp[((size_t)s << 6) | (unsigned)lane]), a0);
    }
    if (!fast) {
        // overflow Phase B (effectively never)
        unsigned on = min(*of_cnt, of_cap);
        for (unsigned i = 0; i < on; i++) {
            if (of_list[2 * i] == (unsigned)d) {
                unsigned s = of_list[2 * i + 1];
                float us = u_arr[s];
                float m = us + vd + bf;
                float g = (fabsf(m) >= 1e-4f) ? ((m > 0.f) ? 1.f : -1.f)
                                              : tier2_sign_stream(tfeat, W_f, (int)s, d, bf);
                float asv = a_src[s * HEADS + q];
                float ap = fmaf(g, asv, adq) + ba;
                float ev = expf(ap > 0.f ? ap : 0.01f * ap);
                a0 = fmaf(ev * g, __half2float(hp[((size_t)s << 6) | (unsigned)lane]), a0);
            }
        }
    }
    out[((size_t)d << 6) | (unsigned)lane] = ((a0 + a1) + (a2 + a3)) * rinv;
}

// ---------------------------------------------------------------------------
extern "C" void kernel_launch(void* const* d_in, const int* in_sizes, int n_in,
                              void* d_out, int out_size, void* d_ws, size_t ws_size,
                              hipStream_t stream)
{
    const float* h       = (const float*)d_in[0];
    const int*   src_idx = (const int*)d_in[1];
    const int*   dst_idx = (const int*)d_in[2];
    const float* W_w     = (const float*)d_in[3];
    const float* b_w     = (const float*)d_in[4];
    const float* W_a     = (const float*)d_in[5];
    const float* b_a     = (const float*)d_in[6];
    const float* W_d     = (const float*)d_in[7];
    const float* b_d     = (const float*)d_in[8];
    const float* W_f     = (const float*)d_in[9];
    const float* b_f     = (const float*)d_in[10];

    int N = in_sizes[0] / F;
    int E = in_sizes[1];
    int nb = (N + 255) / 256;
    int neb = (E + 511) / 512;
    unsigned of_cap = (unsigned)(E / 8);

    char* ws = (char*)d_ws;
    float*    tfeat  = (float*)ws;     ws += (size_t)N * F * 4;          // 12.8MB
    __half*   hp     = (__half*)ws;    ws += (size_t)N * F * 2;          // 6.4MB
    float*    u_arr  = (float*)ws;     ws += (size_t)N * 4;              // 0.2MB
    float*    v_arr  = (float*)ws;     ws += (size_t)N * 4;              // 0.2MB
    float*    a_src  = (float*)ws;     ws += (size_t)N * HEADS * 4;      // 0.8MB
    float*    a_dst  = (float*)ws;     ws += (size_t)N * HEADS * 4;      // 0.8MB
    unsigned* cnt    = (unsigned*)ws;  ws += (size_t)N * 4;              // 0.2MB
    unsigned* of_cnt = (unsigned*)ws;  ws += 64;                         // 64B
    unsigned* slot   = (unsigned*)ws;  ws += (size_t)N * K_SLOT * 4;     // 12.8MB
    unsigned* of_list= (unsigned*)ws;  ws += (size_t)of_cap * 8;         // 1MB

    float* out = (float*)d_out;

    // zero cnt + of_cnt in one async memset (adjacent in layout)
    hipMemsetAsync(cnt, 0, (size_t)N * 4 + 64, stream);

    fused_kernel<<<2 * nb + neb, 256, 0, stream>>>(
        h, W_w, b_w, W_a, W_d, b_d, W_f,
        tfeat, hp, u_arr, v_arr, a_src, a_dst,
        src_idx, dst_idx, cnt, slot, of_list, of_cnt,
        N, E, nb, of_cap);

    dst_gather_kernel<<<(N * 64 + 255) / 256, 256, 0, stream>>>(
        cnt, slot, of_list, of_cnt, u_arr, v_arr, tfeat, W_f, b_f,
        a_src, a_dst, b_a, hp, out, N, of_cap);
}

// Round 15
// 185.137 us; speedup vs baseline: 1.0250x; 1.0250x over previous
//
#include <hip/hip_runtime.h>
#include <hip/hip_fp16.h>

constexpr int F  = 64;   // IN_FEATS == ATT_HEADS*H_FEATS
constexpr int HEADS = 4;
constexpr int SHARDS = 8;    // one slot/counter shard per XCD
constexpr int CAPS = 8;      // per-shard per-dst slot capacity (overflow -> of_list)
constexpr int MAXDEG = 64;   // per-wave LDS slots in gather
constexpr int WSTR = 68;     // padded LDS stride for transposed W (bank-conflict-free-ish)

// ---------------------------------------------------------------------------
// K1 (per node): W_d path. tfeat fp32 (BLAS-order), u/v fp32; zero cnt shards.
// ---------------------------------------------------------------------------
__global__ __launch_bounds__(256) void node_wd_kernel(
    const float* __restrict__ h,
    const float* __restrict__ W_d, const float* __restrict__ b_d,
    const float* __restrict__ W_f,
    float* __restrict__ tfeat,
    float* __restrict__ u_arr, float* __restrict__ v_arr,
    unsigned* __restrict__ cnt, unsigned* __restrict__ of_cnt, int N)
{
    __shared__ float sWT[F * WSTR];  // [j][k] transposed, padded stride
    __shared__ float sb[F];
    __shared__ double swfA[F], swfB[F];

    int tid = threadIdx.x;
    for (int i = tid; i < F * F; i += 256) {
        int k = i >> 6, j = i & 63;
        sWT[j * WSTR + k] = W_d[i];
    }
    if (tid < F) {
        sb[tid] = b_d[tid];
        swfA[tid] = (double)W_f[tid] + (double)W_f[2 * F + tid];
        swfB[tid] = (double)W_f[F + tid] - (double)W_f[2 * F + tid];
    }
    if (blockIdx.x == 0 && tid == 0) *of_cnt = 0;
    __syncthreads();

    int n = blockIdx.x * 256 + tid;
    if (n >= N) return;

#pragma unroll
    for (int x = 0; x < SHARDS; x++) cnt[(size_t)x * N + n] = 0;

    float4 hv[16];
    const float4* h4 = reinterpret_cast<const float4*>(h + (size_t)n * F);
#pragma unroll
    for (int i = 0; i < 16; i++) hv[i] = h4[i];

    double u = 0.0, v = 0.0;
    float4 tq;
    float4* trow = reinterpret_cast<float4*>(tfeat + (size_t)n * F);
#pragma unroll 4
    for (int j = 0; j < F; j++) {
        const float4* row = reinterpret_cast<const float4*>(&sWT[j * WSTR]);
        float t = 0.f;
#pragma unroll
        for (int kk = 0; kk < 16; kk++) {
            float4 w = row[kk];
            float4 x = hv[kk];
            t = fmaf(x.x, w.x, t);
            t = fmaf(x.y, w.y, t);
            t = fmaf(x.z, w.z, t);
            t = fmaf(x.w, w.w, t);
        }
        t = t + sb[j];
        u = fma((double)t, swfA[j], u);
        v = fma((double)t, swfB[j], v);
        if ((j & 3) == 0) tq.x = t;
        else if ((j & 3) == 1) tq.y = t;
        else if ((j & 3) == 2) tq.z = t;
        else { tq.w = t; trow[j >> 2] = tq; }
    }
    u_arr[n] = (float)u;
    v_arr[n] = (float)v;
}

// ---------------------------------------------------------------------------
// Tier-2 sign fallback: literal fp32 192-term sequential FMA in the
// reference's e_feat section order (rare: |fp32 margin| < 1e-4).
// ---------------------------------------------------------------------------
__device__ __noinline__ float tier2_sign(
    const float* __restrict__ tfeat, const float* __restrict__ sWf,
    int s, int d, float bf)
{
    const float4* ts = reinterpret_cast<const float4*>(tfeat + (size_t)s * F);
    const float4* td = reinterpret_cast<const float4*>(tfeat + (size_t)d * F);
    float sv[F];
#pragma unroll
    for (int i = 0; i < 16; i++) {
        float4 a = ts[i];
        sv[4 * i + 0] = a.x; sv[4 * i + 1] = a.y;
        sv[4 * i + 2] = a.z; sv[4 * i + 3] = a.w;
    }
    float acc = 0.f;
#pragma unroll
    for (int j = 0; j < F; j++) acc = fmaf(sv[j], sWf[j], acc);
#pragma unroll
    for (int i = 0; i < 16; i++) {
        float4 a = td[i];
        acc = fmaf(a.x, sWf[F + 4 * i + 0], acc);
        acc = fmaf(a.y, sWf[F + 4 * i + 1], acc);
        acc = fmaf(a.z, sWf[F + 4 * i + 2], acc);
        acc = fmaf(a.w, sWf[F + 4 * i + 3], acc);
    }
#pragma unroll
    for (int i = 0; i < 16; i++) {
        float4 a = td[i];
        acc = fmaf(sv[4 * i + 0] - a.x, sWf[2 * F + 4 * i + 0], acc);
        acc = fmaf(sv[4 * i + 1] - a.y, sWf[2 * F + 4 * i + 1], acc);
        acc = fmaf(sv[4 * i + 2] - a.z, sWf[2 * F + 4 * i + 2], acc);
        acc = fmaf(sv[4 * i + 3] - a.w, sWf[2 * F + 4 * i + 3], acc);
    }
    float sp = acc + bf;
    return (sp > 0.f) ? 1.f : (sp < 0.f ? -1.f : 0.f);
}

// ---------------------------------------------------------------------------
// K2 fused: blocks [0,nbw): node W_w path. blocks [nbw,..): edge path —
// XCD-sharded count (L2-local workgroup-scope atomic) + sign + PACKED slot
// scatter (ushort src + byte sign). Per-XCD working set ~1.4MB -> stays in
// the XCD's 4MB L2 until kernel-end writeback (no line thrash).
// ---------------------------------------------------------------------------
__global__ __launch_bounds__(256) void ww_count_scatter_kernel(
    const float* __restrict__ h,
    const float* __restrict__ W_w, const float* __restrict__ b_w,
    const float* __restrict__ W_a,
    __half* __restrict__ hp,
    float* __restrict__ a_src, float* __restrict__ a_dst,
    const int* __restrict__ src_idx, const int* __restrict__ dst_idx,
    const float* __restrict__ u_arr, const float* __restrict__ v_arr,
    const float* __restrict__ tfeat, const float* __restrict__ W_f,
    const float* __restrict__ b_f,
    unsigned* __restrict__ cnt,
    unsigned short* __restrict__ slot16, unsigned char* __restrict__ sgn8,
    unsigned* __restrict__ of_list, unsigned* __restrict__ of_cnt,
    int N, int E, int nbw, unsigned of_cap)
{
    __shared__ float sWT[F * WSTR];  // W_w blocks: weights; edge blocks: sWf in [0,192)
    __shared__ float sb[F];
    __shared__ float sWa[32];

    int tid = threadIdx.x;

    if (blockIdx.x < nbw) {
        // ---- node W_w path ----
        for (int i = tid; i < F * F; i += 256) {
            int k = i >> 6, j = i & 63;
            sWT[j * WSTR + k] = W_w[i];
        }
        if (tid < F) sb[tid] = b_w[tid];
        if (tid < 32) sWa[tid] = W_a[tid];
        __syncthreads();

        int n = blockIdx.x * 256 + tid;
        if (n >= N) return;

        float4 hv[16];
        const float4* h4 = reinterpret_cast<const float4*>(h + (size_t)n * F);
#pragma unroll
        for (int i = 0; i < 16; i++) hv[i] = h4[i];

        __half2* prow = reinterpret_cast<__half2*>(hp + (size_t)n * F);
#pragma unroll
        for (int qh = 0; qh < 4; qh++) {
            float asq = 0.f, adq = 0.f;
            float pprev = 0.f;
#pragma unroll 4
            for (int jj = 0; jj < 16; jj++) {
                int j = qh * 16 + jj;
                const float4* row = reinterpret_cast<const float4*>(&sWT[j * WSTR]);
                float p = 0.f;
#pragma unroll
                for (int kk = 0; kk < 16; kk++) {
                    float4 w = row[kk];
                    float4 x = hv[kk];
                    p = fmaf(x.x, w.x, p);
                    p = fmaf(x.y, w.y, p);
                    p = fmaf(x.z, w.z, p);
                    p = fmaf(x.w, w.w, p);
                }
                p = p + sb[j];
                asq = fmaf(p, sWa[jj], asq);
                adq = fmaf(p, sWa[16 + jj], adq);
                if ((jj & 1) == 0) pprev = p;
                else prow[j >> 1] = __floats2half2_rn(pprev, p);
            }
            a_src[n * HEADS + qh] = asq;
            a_dst[n * HEADS + qh] = adq;
        }
        return;
    }

    // ---- edge path ----
    float* sWf = sWT;   // reuse first 192 floats
    if (tid < 3 * F) sWf[tid] = W_f[tid];
    __syncthreads();

    unsigned xcc;
    asm volatile("s_getreg_b32 %0, hwreg(HW_REG_XCC_ID)" : "=s"(xcc));
    xcc &= (SHARDS - 1);

    float bf = b_f[0];
    int eb = blockIdx.x - nbw;
    int e0 = eb * 512 + tid;
    int e1 = e0 + 256;
    bool ok0 = e0 < E, ok1 = e1 < E;

    int s0 = 0, d0 = 0, s1 = 0, d1 = 0;
    if (ok0) { s0 = src_idx[e0]; d0 = dst_idx[e0]; }
    if (ok1) { s1 = src_idx[e1]; d1 = dst_idx[e1]; }

    // independent long-latency ops issued up front
    float us0 = ok0 ? u_arr[s0] : 0.f, vd0 = ok0 ? v_arr[d0] : 0.f;
    float us1 = ok1 ? u_arr[s1] : 0.f, vd1 = ok1 ? v_arr[d1] : 0.f;
    unsigned p0 = ok0 ? __hip_atomic_fetch_add(&cnt[(size_t)xcc * N + d0], 1u,
                          __ATOMIC_RELAXED, __HIP_MEMORY_SCOPE_WORKGROUP) : 0u;
    unsigned p1 = ok1 ? __hip_atomic_fetch_add(&cnt[(size_t)xcc * N + d1], 1u,
                          __ATOMIC_RELAXED, __HIP_MEMORY_SCOPE_WORKGROUP) : 0u;

    float m0 = us0 + vd0 + bf;
    float m1 = us1 + vd1 + bf;

    float sg0 = (fabsf(m0) >= 1e-4f) ? ((m0 > 0.f) ? 1.f : -1.f)
                                     : (ok0 ? tier2_sign(tfeat, sWf, s0, d0, bf) : 0.f);
    float sg1 = (fabsf(m1) >= 1e-4f) ? ((m1 > 0.f) ? 1.f : -1.f)
                                     : (ok1 ? tier2_sign(tfeat, sWf, s1, d1, bf) : 0.f);

    if (ok0) {
        unsigned c0 = (sg0 > 0.f) ? 0u : (sg0 < 0.f ? 1u : 2u);
        if (p0 < (unsigned)CAPS) {
            size_t idx = ((size_t)xcc * N + d0) * CAPS + p0;
            slot16[idx] = (unsigned short)s0;
            sgn8[idx] = (unsigned char)c0;
        } else {
            unsigned oi = atomicAdd(of_cnt, 1u);
            if (oi < of_cap) { of_list[2 * oi] = (unsigned)d0; of_list[2 * oi + 1] = (unsigned)s0 | (c0 << 30); }
        }
    }
    if (ok1) {
        unsigned c1 = (sg1 > 0.f) ? 0u : (sg1 < 0.f ? 1u : 2u);
        if (p1 < (unsigned)CAPS) {
            size_t idx = ((size_t)xcc * N + d1) * CAPS + p1;
            slot16[idx] = (unsigned short)s1;
            sgn8[idx] = (unsigned char)c1;
        } else {
            unsigned oi = atomicAdd(of_cnt, 1u);
            if (oi < of_cap) { of_list[2 * oi] = (unsigned)d1; of_list[2 * oi + 1] = (unsigned)s1 | (c1 << 30); }
        }
    }
}

// ---------------------------------------------------------------------------
// K3: one wave per dst. Read 8 shard counts, prefix-map lanes to (shard,pos);
// Phase A: one packed slot per lane -> 4 signed weights in LDS + esum;
// butterfly. Phase B: 8-way ILP LDS-fed fp16 hp gather; one store.
// Slow path (deg>64 or shard overflow — ~1e-3 of dsts at most): recompute
// over clamped slots + of_list.
// ---------------------------------------------------------------------------
__global__ __launch_bounds__(256) void dst_gather_kernel(
    const unsigned* __restrict__ cnt,
    const unsigned short* __restrict__ slot16, const unsigned char* __restrict__ sgn8,
    const unsigned* __restrict__ of_list, const unsigned* __restrict__ of_cnt,
    const float* __restrict__ a_src, const float* __restrict__ a_dst,
    const float* __restrict__ b_a,
    const __half* __restrict__ hp,
    float* __restrict__ out, int N, unsigned of_cap)
{
    __shared__ float sw[4][MAXDEG * 4];     // [wave][slot*4+head] = sgn*ex
    __shared__ unsigned ssrc[4][MAXDEG];    // [wave][slot] = src index

    int tid = threadIdx.x;
    int wslot = tid >> 6;
    int lane = tid & 63;
    int q = lane >> 4;
    int d = (blockIdx.x * 256 + tid) >> 6;
    bool valid = d < N;

    float ba = b_a[0];
    float4 ad4 = make_float4(0.f, 0.f, 0.f, 0.f);
    unsigned csh[SHARDS], pre[SHARDS];
    unsigned deg = 0;
    bool ofl = false;
    if (valid) {
        ad4 = *reinterpret_cast<const float4*>(a_dst + (size_t)d * HEADS);
#pragma unroll
        for (int x = 0; x < SHARDS; x++) {
            unsigned c = cnt[(size_t)x * N + d];
            csh[x] = c; pre[x] = deg; deg += c;
            if (c > (unsigned)CAPS) ofl = true;
        }
    }
    float adq = (q == 0) ? ad4.x : (q == 1) ? ad4.y : (q == 2) ? ad4.z : ad4.w;
    bool fast = valid && (deg <= (unsigned)MAXDEG) && !ofl;

    // Phase A
    float4 p = make_float4(0.f, 0.f, 0.f, 0.f);
    if (fast && lane < (int)deg) {
        int shard = 0; unsigned pos = 0;
#pragma unroll
        for (int x = 0; x < SHARDS; x++)
            if ((unsigned)lane >= pre[x] && (unsigned)lane < pre[x] + csh[x]) {
                shard = x; pos = (unsigned)lane - pre[x];
            }
        size_t idx = ((size_t)shard * N + d) * CAPS + pos;
        unsigned s = slot16[idx];
        unsigned c = sgn8[idx];
        float sgn = (c == 0u) ? 1.f : (c == 1u ? -1.f : 0.f);
        float4 as4 = *reinterpret_cast<const float4*>(a_src + (size_t)s * HEADS);
        float ap0 = fmaf(sgn, as4.x, ad4.x) + ba;
        float ap1 = fmaf(sgn, as4.y, ad4.y) + ba;
        float ap2 = fmaf(sgn, as4.z, ad4.z) + ba;
        float ap3 = fmaf(sgn, as4.w, ad4.w) + ba;
        float e0 = expf(ap0 > 0.f ? ap0 : 0.01f * ap0);
        float e1 = expf(ap1 > 0.f ? ap1 : 0.01f * ap1);
        float e2 = expf(ap2 > 0.f ? ap2 : 0.01f * ap2);
        float e3 = expf(ap3 > 0.f ? ap3 : 0.01f * ap3);
        p = make_float4(e0, e1, e2, e3);
        *reinterpret_cast<float4*>(&sw[wslot][lane * 4]) =
            make_float4(sgn * e0, sgn * e1, sgn * e2, sgn * e3);
        ssrc[wslot][lane] = s;
    }
    if (valid && !fast) {
        // slow path esum: clamped slots + overflow list
        for (int x = 0; x < SHARDS; x++) {
            unsigned cc = min(csh[x], (unsigned)CAPS);
            for (unsigned i = lane; i < cc; i += 64) {
                size_t idx = ((size_t)x * N + d) * CAPS + i;
                unsigned s = slot16[idx];
                unsigned c = sgn8[idx];
                float sgn = (c == 0u) ? 1.f : (c == 1u ? -1.f : 0.f);
                float4 as4 = *reinterpret_cast<const float4*>(a_src + (size_t)s * HEADS);
                float ap0 = fmaf(sgn, as4.x, ad4.x) + ba;
                float ap1 = fmaf(sgn, as4.y, ad4.y) + ba;
                float ap2 = fmaf(sgn, as4.z, ad4.z) + ba;
                float ap3 = fmaf(sgn, as4.w, ad4.w) + ba;
                p.x += expf(ap0 > 0.f ? ap0 : 0.01f * ap0);
                p.y += expf(ap1 > 0.f ? ap1 : 0.01f * ap1);
                p.z += expf(ap2 > 0.f ? ap2 : 0.01f * ap2);
                p.w += expf(ap3 > 0.f ? ap3 : 0.01f * ap3);
            }
        }
        unsigned on = min(*of_cnt, of_cap);
        for (unsigned i = lane; i < on; i += 64) {
            if (of_list[2 * i] == (unsigned)d) {
                unsigned sp = of_list[2 * i + 1];
                unsigned s = sp & 0x3FFFFFFFu;
                unsigned c = sp >> 30;
                float sgn = (c == 0u) ? 1.f : (c == 1u ? -1.f : 0.f);
                float4 as4 = *reinterpret_cast<const float4*>(a_src + (size_t)s * HEADS);
                float ap0 = fmaf(sgn, as4.x, ad4.x) + ba;
                float ap1 = fmaf(sgn, as4.y, ad4.y) + ba;
                float ap2 = fmaf(sgn, as4.z, ad4.z) + ba;
                float ap3 = fmaf(sgn, as4.w, ad4.w) + ba;
                p.x += expf(ap0 > 0.f ? ap0 : 0.01f * ap0);
                p.y += expf(ap1 > 0.f ? ap1 : 0.01f * ap1);
                p.z += expf(ap2 > 0.f ? ap2 : 0.01f * ap2);
                p.w += expf(ap3 > 0.f ? ap3 : 0.01f * ap3);
            }
        }
    }
    __syncthreads();

#pragma unroll
    for (int off = 32; off >= 1; off >>= 1) {
        p.x += __shfl_xor(p.x, off);
        p.y += __shfl_xor(p.y, off);
        p.z += __shfl_xor(p.z, off);
        p.w += __shfl_xor(p.w, off);
    }
    if (!valid) return;

    float esq = (q == 0) ? p.x : (q == 1) ? p.y : (q == 2) ? p.z : p.w;
    float rinv = (deg > 0) ? (1.0f / esq) : 0.f;

    float a0 = 0.f, a1 = 0.f, a2 = 0.f, a3 = 0.f;
    if (fast) {
        const float* swb = &sw[wslot][0];
        const unsigned* ssb = &ssrc[wslot][0];
        unsigned t0 = 0;
        for (; t0 + 8 <= deg; t0 += 8) {
            float w0 = swb[(t0 + 0) * 4 + q], w1 = swb[(t0 + 1) * 4 + q];
            float w2 = swb[(t0 + 2) * 4 + q], w3 = swb[(t0 + 3) * 4 + q];
            float w4 = swb[(t0 + 4) * 4 + q], w5 = swb[(t0 + 5) * 4 + q];
            float w6 = swb[(t0 + 6) * 4 + q], w7 = swb[(t0 + 7) * 4 + q];
            unsigned s0 = ssb[t0 + 0], s1 = ssb[t0 + 1];
            unsigned s2 = ssb[t0 + 2], s3 = ssb[t0 + 3];
            unsigned s4 = ssb[t0 + 4], s5 = ssb[t0 + 5];
            unsigned s6 = ssb[t0 + 6], s7 = ssb[t0 + 7];
            float h0 = __half2float(hp[((size_t)s0 << 6) | (unsigned)lane]);
            float h1 = __half2float(hp[((size_t)s1 << 6) | (unsigned)lane]);
            float h2 = __half2float(hp[((size_t)s2 << 6) | (unsigned)lane]);
            float h3 = __half2float(hp[((size_t)s3 << 6) | (unsigned)lane]);
            float h4 = __half2float(hp[((size_t)s4 << 6) | (unsigned)lane]);
            float h5 = __half2float(hp[((size_t)s5 << 6) | (unsigned)lane]);
            float h6 = __half2float(hp[((size_t)s6 << 6) | (unsigned)lane]);
            float h7 = __half2float(hp[((size_t)s7 << 6) | (unsigned)lane]);
            a0 = fmaf(w0, h0, a0); a1 = fmaf(w1, h1, a1);
            a2 = fmaf(w2, h2, a2); a3 = fmaf(w3, h3, a3);
            a0 = fmaf(w4, h4, a0); a1 = fmaf(w5, h5, a1);
            a2 = fmaf(w6, h6, a2); a3 = fmaf(w7, h7, a3);
        }
        for (; t0 < deg; t0++) {
            float w = swb[t0 * 4 + q];
            unsigned s = ssb[t0];
            a0 = fmaf(w, __half2float(hp[((size_t)s << 6) | (unsigned)lane]), a0);
        }
    } else {
        // slow path: serial recompute over clamped slots + of_list
        for (int x = 0; x < SHARDS; x++) {
            unsigned cc = min(csh[x], (unsigned)CAPS);
            for (unsigned i = 0; i < cc; i++) {
                size_t idx = ((size_t)x * N + d) * CAPS + i;
                unsigned s = slot16[idx];
                unsigned c = sgn8[idx];
                float g = (c == 0u) ? 1.f : (c == 1u ? -1.f : 0.f);
                float asv = a_src[s * HEADS + q];
                float ap = fmaf(g, asv, adq) + ba;
                float ev = expf(ap > 0.f ? ap : 0.01f * ap);
                a0 = fmaf(ev * g, __half2float(hp[((size_t)s << 6) | (unsigned)lane]), a0);
            }
        }
        unsigned on = min(*of_cnt, of_cap);
        for (unsigned i = 0; i < on; i++) {
            if (of_list[2 * i] == (unsigned)d) {
                unsigned sp = of_list[2 * i + 1];
                unsigned s = sp & 0x3FFFFFFFu;
                unsigned c = sp >> 30;
                float g = (c == 0u) ? 1.f : (c == 1u ? -1.f : 0.f);
                float asv = a_src[s * HEADS + q];
                float ap = fmaf(g, asv, adq) + ba;
                float ev = expf(ap > 0.f ? ap : 0.01f * ap);
                a0 = fmaf(ev * g, __half2float(hp[((size_t)s << 6) | (unsigned)lane]), a0);
            }
        }
    }
    out[((size_t)d << 6) | (unsigned)lane] = ((a0 + a1) + (a2 + a3)) * rinv;
}

// ---------------------------------------------------------------------------
extern "C" void kernel_launch(void* const* d_in, const int* in_sizes, int n_in,
                              void* d_out, int out_size, void* d_ws, size_t ws_size,
                              hipStream_t stream)
{
    const float* h       = (const float*)d_in[0];
    const int*   src_idx = (const int*)d_in[1];
    const int*   dst_idx = (const int*)d_in[2];
    const float* W_w     = (const float*)d_in[3];
    const float* b_w     = (const float*)d_in[4];
    const float* W_a     = (const float*)d_in[5];
    const float* b_a     = (const float*)d_in[6];
    const float* W_d     = (const float*)d_in[7];
    const float* b_d     = (const float*)d_in[8];
    const float* W_f     = (const float*)d_in[9];
    const float* b_f     = (const float*)d_in[10];

    int N = in_sizes[0] / F;
    int E = in_sizes[1];
    int nb = (N + 255) / 256;
    int neb = (E + 511) / 512;
    unsigned of_cap = (unsigned)(E / 8);

    char* ws = (char*)d_ws;
    float*          tfeat  = (float*)ws;          ws += (size_t)N * F * 4;            // 12.8MB
    __half*         hp     = (__half*)ws;         ws += (size_t)N * F * 2;            // 6.4MB
    float*          u_arr  = (float*)ws;          ws += (size_t)N * 4;                // 0.2MB
    float*          v_arr  = (float*)ws;          ws += (size_t)N * 4;                // 0.2MB
    float*          a_src  = (float*)ws;          ws += (size_t)N * HEADS * 4;        // 0.8MB
    float*          a_dst  = (float*)ws;          ws += (size_t)N * HEADS * 4;        // 0.8MB
    unsigned*       cnt    = (unsigned*)ws;       ws += (size_t)SHARDS * N * 4;       // 1.6MB
    unsigned*       of_cnt = (unsigned*)ws;       ws += 64;                           // 64B
    unsigned short* slot16 = (unsigned short*)ws; ws += (size_t)SHARDS * N * CAPS * 2; // 6.4MB
    unsigned char*  sgn8   = (unsigned char*)ws;  ws += (size_t)SHARDS * N * CAPS;     // 3.2MB
    unsigned*       of_list= (unsigned*)ws;       ws += (size_t)of_cap * 8;            // 1MB

    float* out = (float*)d_out;

    node_wd_kernel<<<nb, 256, 0, stream>>>(
        h, W_d, b_d, W_f, tfeat, u_arr, v_arr, cnt, of_cnt, N);

    ww_count_scatter_kernel<<<nb + neb, 256, 0, stream>>>(
        h, W_w, b_w, W_a, hp, a_src, a_dst,
        src_idx, dst_idx, u_arr, v_arr, tfeat, W_f, b_f,
        cnt, slot16, sgn8, of_list, of_cnt, N, E, nb, of_cap);

    dst_gather_kernel<<<(N * 64 + 255) / 256, 256, 0, stream>>>(
        cnt, slot16, sgn8, of_list, of_cnt, a_src, a_dst, b_a, hp, out, N, of_cap);
}

// Round 17
// 135.504 us; speedup vs baseline: 1.4004x; 1.3663x over previous
//
#include <hip/hip_runtime.h>
#include <hip/hip_fp16.h>

constexpr int F  = 64;   // IN_FEATS == ATT_HEADS*H_FEATS
constexpr int HEADS = 4;
constexpr int SHARDS = 8;    // one slot/counter shard per XCD
constexpr int CAPS = 16;     // per-shard per-dst slots; Pois(2.5) P(>16)~1e-8 -> never overflows
constexpr int MAXDEG = 64;   // per-wave LDS slots in gather (deg Pois(20), P(>64)~1e-15)
constexpr int WSTR = 68;     // padded LDS stride for transposed W (bank-conflict fix)

typedef float f32x4 __attribute__((ext_vector_type(4)));   // native vec for nt-store

// ---------------------------------------------------------------------------
// K1 (per node): W_d path. tfeat fp32 (BLAS-order, nt stores), u/v fp32;
// zero cnt shards + of_cnt.
// ---------------------------------------------------------------------------
__global__ __launch_bounds__(256) void node_wd_kernel(
    const float* __restrict__ h,
    const float* __restrict__ W_d, const float* __restrict__ b_d,
    const float* __restrict__ W_f,
    float* __restrict__ tfeat,
    float* __restrict__ u_arr, float* __restrict__ v_arr,
    unsigned* __restrict__ cnt, unsigned* __restrict__ of_cnt, int N)
{
    __shared__ float sWT[F * WSTR];  // [j][k] transposed, padded stride
    __shared__ float sb[F];
    __shared__ double swfA[F], swfB[F];

    int tid = threadIdx.x;
    for (int i = tid; i < F * F; i += 256) {
        int k = i >> 6, j = i & 63;
        sWT[j * WSTR + k] = W_d[i];
    }
    if (tid < F) {
        sb[tid] = b_d[tid];
        swfA[tid] = (double)W_f[tid] + (double)W_f[2 * F + tid];
        swfB[tid] = (double)W_f[F + tid] - (double)W_f[2 * F + tid];
    }
    if (blockIdx.x == 0 && tid == 0) *of_cnt = 0;
    __syncthreads();

    int n = blockIdx.x * 256 + tid;
    if (n >= N) return;

#pragma unroll
    for (int x = 0; x < SHARDS; x++) cnt[(size_t)x * N + n] = 0;

    float4 hv[16];
    const float4* h4 = reinterpret_cast<const float4*>(h + (size_t)n * F);
#pragma unroll
    for (int i = 0; i < 16; i++) hv[i] = h4[i];

    double u = 0.0, v = 0.0;
    float tq0 = 0.f, tq1 = 0.f, tq2 = 0.f;
    f32x4* trow = reinterpret_cast<f32x4*>(tfeat + (size_t)n * F);
#pragma unroll 4
    for (int j = 0; j < F; j++) {
        const float4* row = reinterpret_cast<const float4*>(&sWT[j * WSTR]);
        float t = 0.f;
#pragma unroll
        for (int kk = 0; kk < 16; kk++) {
            float4 w = row[kk];
            float4 x = hv[kk];
            t = fmaf(x.x, w.x, t);
            t = fmaf(x.y, w.y, t);
            t = fmaf(x.z, w.z, t);
            t = fmaf(x.w, w.w, t);
        }
        t = t + sb[j];
        u = fma((double)t, swfA[j], u);
        v = fma((double)t, swfB[j], v);
        if ((j & 3) == 0) tq0 = t;
        else if ((j & 3) == 1) tq1 = t;
        else if ((j & 3) == 2) tq2 = t;
        else {
            f32x4 tv = {tq0, tq1, tq2, t};
            __builtin_nontemporal_store(tv, &trow[j >> 2]);
        }
    }
    u_arr[n] = (float)u;    // read randomly by K2 -> keep cacheable
    v_arr[n] = (float)v;
}

// ---------------------------------------------------------------------------
// Tier-2 sign fallback, STREAMING form (~12 VGPRs, ~200 edges total):
// literal fp32 192-term sequential FMA in the reference's e_feat section
// order — bit-identical to the buffered form (verified r14: absmax same).
// ---------------------------------------------------------------------------
__device__ __noinline__ float tier2_sign_stream(
    const float* __restrict__ tfeat, const float* __restrict__ W_f,
    int s, int d, float bf)
{
    const float4* ts = reinterpret_cast<const float4*>(tfeat + (size_t)s * F);
    const float4* td = reinterpret_cast<const float4*>(tfeat + (size_t)d * F);
    const float4* wf = reinterpret_cast<const float4*>(W_f);
    float acc = 0.f;
#pragma unroll
    for (int i = 0; i < 16; i++) {
        float4 a = ts[i], w = wf[i];
        acc = fmaf(a.x, w.x, acc); acc = fmaf(a.y, w.y, acc);
        acc = fmaf(a.z, w.z, acc); acc = fmaf(a.w, w.w, acc);
    }
#pragma unroll
    for (int i = 0; i < 16; i++) {
        float4 a = td[i], w = wf[16 + i];
        acc = fmaf(a.x, w.x, acc); acc = fmaf(a.y, w.y, acc);
        acc = fmaf(a.z, w.z, acc); acc = fmaf(a.w, w.w, acc);
    }
#pragma unroll
    for (int i = 0; i < 16; i++) {
        float4 a = ts[i], b = td[i], w = wf[32 + i];
        acc = fmaf(a.x - b.x, w.x, acc); acc = fmaf(a.y - b.y, w.y, acc);
        acc = fmaf(a.z - b.z, w.z, acc); acc = fmaf(a.w - b.w, w.w, acc);
    }
    float sp = acc + bf;
    return (sp > 0.f) ? 1.f : (sp < 0.f ? -1.f : 0.f);
}

// ---------------------------------------------------------------------------
// K2 fused: blocks [0,nbw): node W_w path (hp fp16 nt-stored, a_src/a_dst).
// blocks [nbw,..): edge path — XCD-sharded count (L2-local workgroup-scope
// atomic; shard region 3.4MB/XCD fits the 4MB L2) + sign + 4B slot scatter.
// Edge blocks touch no LDS (streaming tier2), no __syncthreads.
// ---------------------------------------------------------------------------
__global__ __launch_bounds__(256) void ww_count_scatter_kernel(
    const float* __restrict__ h,
    const float* __restrict__ W_w, const float* __restrict__ b_w,
    const float* __restrict__ W_a,
    __half* __restrict__ hp,
    float* __restrict__ a_src, float* __restrict__ a_dst,
    const int* __restrict__ src_idx, const int* __restrict__ dst_idx,
    const float* __restrict__ u_arr, const float* __restrict__ v_arr,
    const float* __restrict__ tfeat, const float* __restrict__ W_f,
    const float* __restrict__ b_f,
    unsigned* __restrict__ cnt, unsigned* __restrict__ slot,
    unsigned* __restrict__ of_list, unsigned* __restrict__ of_cnt,
    int N, int E, int nbw, unsigned of_cap)
{
    __shared__ float sWT[F * WSTR];
    __shared__ float sb[F];
    __shared__ float sWa[32];

    int tid = threadIdx.x;

    if (blockIdx.x < nbw) {
        // ---- node W_w path ----
        for (int i = tid; i < F * F; i += 256) {
            int k = i >> 6, j = i & 63;
            sWT[j * WSTR + k] = W_w[i];
        }
        if (tid < F) sb[tid] = b_w[tid];
        if (tid < 32) sWa[tid] = W_a[tid];
        __syncthreads();

        int n = blockIdx.x * 256 + tid;
        if (n >= N) return;

        float4 hv[16];
        const float4* h4 = reinterpret_cast<const float4*>(h + (size_t)n * F);
#pragma unroll
        for (int i = 0; i < 16; i++) hv[i] = h4[i];

        unsigned* prow = reinterpret_cast<unsigned*>(hp + (size_t)n * F);
#pragma unroll
        for (int qh = 0; qh < 4; qh++) {
            float asq = 0.f, adq = 0.f;
            float pprev = 0.f;
#pragma unroll 4
            for (int jj = 0; jj < 16; jj++) {
                int j = qh * 16 + jj;
                const float4* row = reinterpret_cast<const float4*>(&sWT[j * WSTR]);
                float p = 0.f;
#pragma unroll
                for (int kk = 0; kk < 16; kk++) {
                    float4 w = row[kk];
                    float4 x = hv[kk];
                    p = fmaf(x.x, w.x, p);
                    p = fmaf(x.y, w.y, p);
                    p = fmaf(x.z, w.z, p);
                    p = fmaf(x.w, w.w, p);
                }
                p = p + sb[j];
                asq = fmaf(p, sWa[jj], asq);
                adq = fmaf(p, sWa[16 + jj], adq);
                if ((jj & 1) == 0) pprev = p;
                else {
                    __half2 hh = __floats2half2_rn(pprev, p);
                    unsigned bits;
                    __builtin_memcpy(&bits, &hh, 4);
                    __builtin_nontemporal_store(bits, &prow[j >> 1]);
                }
            }
            a_src[n * HEADS + qh] = asq;
            a_dst[n * HEADS + qh] = adq;
        }
        return;
    }

    // ---- edge path (no LDS, no barrier) ----
    unsigned xcc;
    asm volatile("s_getreg_b32 %0, hwreg(HW_REG_XCC_ID)" : "=s"(xcc));
    xcc &= (SHARDS - 1);

    float bf = b_f[0];
    int eb = blockIdx.x - nbw;
    int e0 = eb * 512 + tid;
    int e1 = e0 + 256;
    bool ok0 = e0 < E, ok1 = e1 < E;

    int s0 = 0, d0 = 0, s1 = 0, d1 = 0;
    if (ok0) { s0 = src_idx[e0]; d0 = dst_idx[e0]; }
    if (ok1) { s1 = src_idx[e1]; d1 = dst_idx[e1]; }

    // independent long-latency ops issued up front
    float us0 = ok0 ? u_arr[s0] : 0.f, vd0 = ok0 ? v_arr[d0] : 0.f;
    float us1 = ok1 ? u_arr[s1] : 0.f, vd1 = ok1 ? v_arr[d1] : 0.f;
    unsigned p0 = ok0 ? __hip_atomic_fetch_add(&cnt[(size_t)xcc * N + d0], 1u,
                          __ATOMIC_RELAXED, __HIP_MEMORY_SCOPE_WORKGROUP) : 0u;
    unsigned p1 = ok1 ? __hip_atomic_fetch_add(&cnt[(size_t)xcc * N + d1], 1u,
                          __ATOMIC_RELAXED, __HIP_MEMORY_SCOPE_WORKGROUP) : 0u;

    float m0 = us0 + vd0 + bf;
    float m1 = us1 + vd1 + bf;

    float sg0 = (fabsf(m0) >= 1e-4f) ? ((m0 > 0.f) ? 1.f : -1.f)
              : (ok0 ? tier2_sign_stream(tfeat, W_f, s0, d0, bf) : 0.f);
    float sg1 = (fabsf(m1) >= 1e-4f) ? ((m1 > 0.f) ? 1.f : -1.f)
              : (ok1 ? tier2_sign_stream(tfeat, W_f, s1, d1, bf) : 0.f);

    if (ok0) {
        unsigned c0 = (sg0 > 0.f) ? 0u : (sg0 < 0.f ? 1u : 2u);
        unsigned val = (unsigned)s0 | (c0 << 30);
        if (p0 < (unsigned)CAPS) slot[((size_t)xcc * N + d0) * CAPS + p0] = val;
        else {
            unsigned oi = atomicAdd(of_cnt, 1u);
            if (oi < of_cap) { of_list[2 * oi] = (unsigned)d0; of_list[2 * oi + 1] = val; }
        }
    }
    if (ok1) {
        unsigned c1 = (sg1 > 0.f) ? 0u : (sg1 < 0.f ? 1u : 2u);
        unsigned val = (unsigned)s1 | (c1 << 30);
        if (p1 < (unsigned)CAPS) slot[((size_t)xcc * N + d1) * CAPS + p1] = val;
        else {
            unsigned oi = atomicAdd(of_cnt, 1u);
            if (oi < of_cap) { of_list[2 * oi] = (unsigned)d1; of_list[2 * oi + 1] = val; }
        }
    }
}

// ---------------------------------------------------------------------------
// K3: one wave per dst (exact r13). Read 8 shard counts, prefix-map lanes to
// (shard,pos); Phase A: one 4B slot per lane -> 4 signed weights in LDS +
// esum; butterfly. Phase B: 8-way ILP LDS-fed fp16 hp gather; one store.
// Slow path (deg>64 or shard>16 — statistically unreachable): clamped slots
// + of_list recompute.
// ---------------------------------------------------------------------------
__global__ __launch_bounds__(256) void dst_gather_kernel(
    const unsigned* __restrict__ cnt,
    const unsigned* __restrict__ slot,
    const unsigned* __restrict__ of_list, const unsigned* __restrict__ of_cnt,
    const float* __restrict__ a_src, const float* __restrict__ a_dst,
    const float* __restrict__ b_a,
    const __half* __restrict__ hp,
    float* __restrict__ out, int N, unsigned of_cap)
{
    __shared__ float sw[4][MAXDEG * 4];     // [wave][slot*4+head] = sgn*ex
    __shared__ unsigned ssrc[4][MAXDEG];    // [wave][slot] = src index

    int tid = threadIdx.x;
    int wslot = tid >> 6;
    int lane = tid & 63;
    int q = lane >> 4;
    int d = (blockIdx.x * 256 + tid) >> 6;
    bool valid = d < N;

    float ba = b_a[0];
    float4 ad4 = make_float4(0.f, 0.f, 0.f, 0.f);
    unsigned csh[SHARDS], pre[SHARDS];
    unsigned deg = 0;
    bool ofl = false;
    if (valid) {
        ad4 = *reinterpret_cast<const float4*>(a_dst + (size_t)d * HEADS);
#pragma unroll
        for (int x = 0; x < SHARDS; x++) {
            unsigned c = cnt[(size_t)x * N + d];
            csh[x] = c; pre[x] = deg; deg += c;
            if (c > (unsigned)CAPS) ofl = true;
        }
    }
    float adq = (q == 0) ? ad4.x : (q == 1) ? ad4.y : (q == 2) ? ad4.z : ad4.w;
    bool fast = valid && (deg <= (unsigned)MAXDEG) && !ofl;

    // Phase A
    float4 p = make_float4(0.f, 0.f, 0.f, 0.f);
    if (fast && lane < (int)deg) {
        int shard = 0; unsigned pos = 0;
#pragma unroll
        for (int x = 0; x < SHARDS; x++)
            if ((unsigned)lane >= pre[x] && (unsigned)lane < pre[x] + csh[x]) {
                shard = x; pos = (unsigned)lane - pre[x];
            }
        unsigned sp = slot[((size_t)shard * N + d) * CAPS + pos];
        unsigned s = sp & 0x3FFFFFFFu;
        unsigned c = sp >> 30;
        float sgn = (c == 0u) ? 1.f : (c == 1u ? -1.f : 0.f);
        float4 as4 = *reinterpret_cast<const float4*>(a_src + (size_t)s * HEADS);
        float ap0 = fmaf(sgn, as4.x, ad4.x) + ba;
        float ap1 = fmaf(sgn, as4.y, ad4.y) + ba;
        float ap2 = fmaf(sgn, as4.z, ad4.z) + ba;
        float ap3 = fmaf(sgn, as4.w, ad4.w) + ba;
        float e0 = expf(ap0 > 0.f ? ap0 : 0.01f * ap0);
        float e1 = expf(ap1 > 0.f ? ap1 : 0.01f * ap1);
        float e2 = expf(ap2 > 0.f ? ap2 : 0.01f * ap2);
        float e3 = expf(ap3 > 0.f ? ap3 : 0.01f * ap3);
        p = make_float4(e0, e1, e2, e3);
        *reinterpret_cast<float4*>(&sw[wslot][lane * 4]) =
            make_float4(sgn * e0, sgn * e1, sgn * e2, sgn * e3);
        ssrc[wslot][lane] = s;
    }
    if (valid && !fast) {
        for (int x = 0; x < SHARDS; x++) {
            unsigned cc = min(csh[x], (unsigned)CAPS);
            for (unsigned i = lane; i < cc; i += 64) {
                unsigned sp = slot[((size_t)x * N + d) * CAPS + i];
                unsigned s = sp & 0x3FFFFFFFu;
                unsigned c = sp >> 30;
                float sgn = (c == 0u) ? 1.f : (c == 1u ? -1.f : 0.f);
                float4 as4 = *reinterpret_cast<const float4*>(a_src + (size_t)s * HEADS);
                float ap0 = fmaf(sgn, as4.x, ad4.x) + ba;
                float ap1 = fmaf(sgn, as4.y, ad4.y) + ba;
                float ap2 = fmaf(sgn, as4.z, ad4.z) + ba;
                float ap3 = fmaf(sgn, as4.w, ad4.w) + ba;
                p.x += expf(ap0 > 0.f ? ap0 : 0.01f * ap0);
                p.y += expf(ap1 > 0.f ? ap1 : 0.01f * ap1);
                p.z += expf(ap2 > 0.f ? ap2 : 0.01f * ap2);
                p.w += expf(ap3 > 0.f ? ap3 : 0.01f * ap3);
            }
        }
        unsigned on = min(*of_cnt, of_cap);
        for (unsigned i = lane; i < on; i += 64) {
            if (of_list[2 * i] == (unsigned)d) {
                unsigned sp = of_list[2 * i + 1];
                unsigned s = sp & 0x3FFFFFFFu;
                unsigned c = sp >> 30;
                float sgn = (c == 0u) ? 1.f : (c == 1u ? -1.f : 0.f);
                float4 as4 = *reinterpret_cast<const float4*>(a_src + (size_t)s * HEADS);
                float ap0 = fmaf(sgn, as4.x, ad4.x) + ba;
                float ap1 = fmaf(sgn, as4.y, ad4.y) + ba;
                float ap2 = fmaf(sgn, as4.z, ad4.z) + ba;
                float ap3 = fmaf(sgn, as4.w, ad4.w) + ba;
                p.x += expf(ap0 > 0.f ? ap0 : 0.01f * ap0);
                p.y += expf(ap1 > 0.f ? ap1 : 0.01f * ap1);
                p.z += expf(ap2 > 0.f ? ap2 : 0.01f * ap2);
                p.w += expf(ap3 > 0.f ? ap3 : 0.01f * ap3);
            }
        }
    }
    __syncthreads();

#pragma unroll
    for (int off = 32; off >= 1; off >>= 1) {
        p.x += __shfl_xor(p.x, off);
        p.y += __shfl_xor(p.y, off);
        p.z += __shfl_xor(p.z, off);
        p.w += __shfl_xor(p.w, off);
    }
    if (!valid) return;

    float esq = (q == 0) ? p.x : (q == 1) ? p.y : (q == 2) ? p.z : p.w;
    float rinv = (deg > 0) ? (1.0f / esq) : 0.f;

    float a0 = 0.f, a1 = 0.f, a2 = 0.f, a3 = 0.f;
    if (fast) {
        const float* swb = &sw[wslot][0];
        const unsigned* ssb = &ssrc[wslot][0];
        unsigned t0 = 0;
        for (; t0 + 8 <= deg; t0 += 8) {
            float w0 = swb[(t0 + 0) * 4 + q], w1 = swb[(t0 + 1) * 4 + q];
            float w2 = swb[(t0 + 2) * 4 + q], w3 = swb[(t0 + 3) * 4 + q];
            float w4 = swb[(t0 + 4) * 4 + q], w5 = swb[(t0 + 5) * 4 + q];
            float w6 = swb[(t0 + 6) * 4 + q], w7 = swb[(t0 + 7) * 4 + q];
            unsigned s0 = ssb[t0 + 0], s1 = ssb[t0 + 1];
            unsigned s2 = ssb[t0 + 2], s3 = ssb[t0 + 3];
            unsigned s4 = ssb[t0 + 4], s5 = ssb[t0 + 5];
            unsigned s6 = ssb[t0 + 6], s7 = ssb[t0 + 7];
            float h0 = __half2float(hp[((size_t)s0 << 6) | (unsigned)lane]);
            float h1 = __half2float(hp[((size_t)s1 << 6) | (unsigned)lane]);
            float h2 = __half2float(hp[((size_t)s2 << 6) | (unsigned)lane]);
            float h3 = __half2float(hp[((size_t)s3 << 6) | (unsigned)lane]);
            float h4 = __half2float(hp[((size_t)s4 << 6) | (unsigned)lane]);
            float h5 = __half2float(hp[((size_t)s5 << 6) | (unsigned)lane]);
            float h6 = __half2float(hp[((size_t)s6 << 6) | (unsigned)lane]);
            float h7 = __half2float(hp[((size_t)s7 << 6) | (unsigned)lane]);
            a0 = fmaf(w0, h0, a0); a1 = fmaf(w1, h1, a1);
            a2 = fmaf(w2, h2, a2); a3 = fmaf(w3, h3, a3);
            a0 = fmaf(w4, h4, a0); a1 = fmaf(w5, h5, a1);
            a2 = fmaf(w6, h6, a2); a3 = fmaf(w7, h7, a3);
        }
        for (; t0 < deg; t0++) {
            float w = swb[t0 * 4 + q];
            unsigned s = ssb[t0];
            a0 = fmaf(w, __half2float(hp[((size_t)s << 6) | (unsigned)lane]), a0);
        }
    } else {
        for (int x = 0; x < SHARDS; x++) {
            unsigned cc = min(csh[x], (unsigned)CAPS);
            for (unsigned i = 0; i < cc; i++) {
                unsigned sp = slot[((size_t)x * N + d) * CAPS + i];
                unsigned s = sp & 0x3FFFFFFFu;
                unsigned c = sp >> 30;
                float g = (c == 0u) ? 1.f : (c == 1u ? -1.f : 0.f);
                float asv = a_src[s * HEADS + q];
                float ap = fmaf(g, asv, adq) + ba;
                float ev = expf(ap > 0.f ? ap : 0.01f * ap);
                a0 = fmaf(ev * g, __half2float(hp[((size_t)s << 6) | (unsigned)lane]), a0);
            }
        }
        unsigned on = min(*of_cnt, of_cap);
        for (unsigned i = 0; i < on; i++) {
            if (of_list[2 * i] == (unsigned)d) {
                unsigned sp = of_list[2 * i + 1];
                unsigned s = sp & 0x3FFFFFFFu;
                unsigned c = sp >> 30;
                float g = (c == 0u) ? 1.f : (c == 1u ? -1.f : 0.f);
                float asv = a_src[s * HEADS + q];
                float ap = fmaf(g, asv, adq) + ba;
                float ev = expf(ap > 0.f ? ap : 0.01f * ap);
                a0 = fmaf(ev * g, __half2float(hp[((size_t)s << 6) | (unsigned)lane]), a0);
            }
        }
    }
    out[((size_t)d << 6) | (unsigned)lane] = ((a0 + a1) + (a2 + a3)) * rinv;
}

// ---------------------------------------------------------------------------
extern "C" void kernel_launch(void* const* d_in, const int* in_sizes, int n_in,
                              void* d_out, int out_size, void* d_ws, size_t ws_size,
                              hipStream_t stream)
{
    const float* h       = (const float*)d_in[0];
    const int*   src_idx = (const int*)d_in[1];
    const int*   dst_idx = (const int*)d_in[2];
    const float* W_w     = (const float*)d_in[3];
    const float* b_w     = (const float*)d_in[4];
    const float* W_a     = (const float*)d_in[5];
    const float* b_a     = (const float*)d_in[6];
    const float* W_d     = (const float*)d_in[7];
    const float* b_d     = (const float*)d_in[8];
    const float* W_f     = (const float*)d_in[9];
    const float* b_f     = (const float*)d_in[10];

    int N = in_sizes[0] / F;
    int E = in_sizes[1];
    int nb = (N + 255) / 256;
    int neb = (E + 511) / 512;
    unsigned of_cap = (unsigned)(E / 8);

    char* ws = (char*)d_ws;
    float*    tfeat  = (float*)ws;     ws += (size_t)N * F * 4;               // 12.8MB
    __half*   hp     = (__half*)ws;    ws += (size_t)N * F * 2;               // 6.4MB
    float*    u_arr  = (float*)ws;     ws += (size_t)N * 4;                   // 0.2MB
    float*    v_arr  = (float*)ws;     ws += (size_t)N * 4;                   // 0.2MB
    float*    a_src  = (float*)ws;     ws += (size_t)N * HEADS * 4;           // 0.8MB
    float*    a_dst  = (float*)ws;     ws += (size_t)N * HEADS * 4;           // 0.8MB
    unsigned* cnt    = (unsigned*)ws;  ws += (size_t)SHARDS * N * 4;          // 1.6MB
    unsigned* of_cnt = (unsigned*)ws;  ws += 64;                              // 64B
    unsigned* slot   = (unsigned*)ws;  ws += (size_t)SHARDS * N * CAPS * 4;   // 25.6MB
    unsigned* of_list= (unsigned*)ws;  ws += (size_t)of_cap * 8;              // 1MB

    float* out = (float*)d_out;

    node_wd_kernel<<<nb, 256, 0, stream>>>(
        h, W_d, b_d, W_f, tfeat, u_arr, v_arr, cnt, of_cnt, N);

    ww_count_scatter_kernel<<<nb + neb, 256, 0, stream>>>(
        h, W_w, b_w, W_a, hp, a_src, a_dst,
        src_idx, dst_idx, u_arr, v_arr, tfeat, W_f, b_f,
        cnt, slot, of_list, of_cnt, N, E, nb, of_cap);

    dst_gather_kernel<<<(N * 64 + 255) / 256, 256, 0, stream>>>(
        cnt, slot, of_list, of_cnt, a_src, a_dst, b_a, hp, out, N, of_cap);
}

// Round 18
// 128.027 us; speedup vs baseline: 1.4822x; 1.0584x over previous
//
#include <hip/hip_runtime.h>
#include <hip/hip_fp16.h>

constexpr int F  = 64;   // IN_FEATS == ATT_HEADS*H_FEATS
constexpr int HEADS = 4;
constexpr int SHARDS = 8;    // one slot/counter shard per XCD
constexpr int CAPS = 16;     // per-shard per-dst slots; Pois(2.5) P(>16)~1e-8
constexpr int MAXDEG = 64;   // per-wave LDS slots in gather

// ---------------------------------------------------------------------------
// K1 (per node): W_d path. tfeat fp32 (BLAS-order), u/v fp32; zero cnt+of_cnt.
// ---------------------------------------------------------------------------
__global__ __launch_bounds__(256) void node_wd_kernel(
    const float* __restrict__ h,
    const float* __restrict__ W_d, const float* __restrict__ b_d,
    const float* __restrict__ W_f,
    float* __restrict__ tfeat,
    float* __restrict__ u_arr, float* __restrict__ v_arr,
    unsigned* __restrict__ cnt, unsigned* __restrict__ of_cnt, int N)
{
    __shared__ float sWT[F * F];     // [j][k] transposed
    __shared__ float sb[F];
    __shared__ double swfA[F], swfB[F];

    int tid = threadIdx.x;
    for (int i = tid; i < F * F; i += 256) {
        int k = i >> 6, j = i & 63;
        sWT[j * F + k] = W_d[i];
    }
    if (tid < F) {
        sb[tid] = b_d[tid];
        swfA[tid] = (double)W_f[tid] + (double)W_f[2 * F + tid];
        swfB[tid] = (double)W_f[F + tid] - (double)W_f[2 * F + tid];
    }
    if (blockIdx.x == 0 && tid == 0) *of_cnt = 0;
    __syncthreads();

    int n = blockIdx.x * 256 + tid;
    if (n >= N) return;

#pragma unroll
    for (int x = 0; x < SHARDS; x++) cnt[(size_t)x * N + n] = 0;

    float4 hv[16];
    const float4* h4 = reinterpret_cast<const float4*>(h + (size_t)n * F);
#pragma unroll
    for (int i = 0; i < 16; i++) hv[i] = h4[i];

    double u = 0.0, v = 0.0;
    float4 tq;
    float4* trow = reinterpret_cast<float4*>(tfeat + (size_t)n * F);
#pragma unroll 4
    for (int j = 0; j < F; j++) {
        const float4* row = reinterpret_cast<const float4*>(&sWT[j * F]);
        float t = 0.f;
#pragma unroll
        for (int kk = 0; kk < 16; kk++) {
            float4 w = row[kk];
            float4 x = hv[kk];
            t = fmaf(x.x, w.x, t);
            t = fmaf(x.y, w.y, t);
            t = fmaf(x.z, w.z, t);
            t = fmaf(x.w, w.w, t);
        }
        t = t + sb[j];
        u = fma((double)t, swfA[j], u);
        v = fma((double)t, swfB[j], v);
        if ((j & 3) == 0) tq.x = t;
        else if ((j & 3) == 1) tq.y = t;
        else if ((j & 3) == 2) tq.z = t;
        else { tq.w = t; trow[j >> 2] = tq; }
    }
    u_arr[n] = (float)u;
    v_arr[n] = (float)v;
}

// ---------------------------------------------------------------------------
// Tier-2 sign fallback: literal fp32 192-term sequential FMA in the
// reference's e_feat section order (rare: |fp32 margin| < 1e-4).
// ---------------------------------------------------------------------------
__device__ __noinline__ float tier2_sign(
    const float* __restrict__ tfeat, const float* __restrict__ sWf,
    int s, int d, float bf)
{
    const float4* ts = reinterpret_cast<const float4*>(tfeat + (size_t)s * F);
    const float4* td = reinterpret_cast<const float4*>(tfeat + (size_t)d * F);
    float sv[F];
#pragma unroll
    for (int i = 0; i < 16; i++) {
        float4 a = ts[i];
        sv[4 * i + 0] = a.x; sv[4 * i + 1] = a.y;
        sv[4 * i + 2] = a.z; sv[4 * i + 3] = a.w;
    }
    float acc = 0.f;
#pragma unroll
    for (int j = 0; j < F; j++) acc = fmaf(sv[j], sWf[j], acc);
#pragma unroll
    for (int i = 0; i < 16; i++) {
        float4 a = td[i];
        acc = fmaf(a.x, sWf[F + 4 * i + 0], acc);
        acc = fmaf(a.y, sWf[F + 4 * i + 1], acc);
        acc = fmaf(a.z, sWf[F + 4 * i + 2], acc);
        acc = fmaf(a.w, sWf[F + 4 * i + 3], acc);
    }
#pragma unroll
    for (int i = 0; i < 16; i++) {
        float4 a = td[i];
        acc = fmaf(sv[4 * i + 0] - a.x, sWf[2 * F + 4 * i + 0], acc);
        acc = fmaf(sv[4 * i + 1] - a.y, sWf[2 * F + 4 * i + 1], acc);
        acc = fmaf(sv[4 * i + 2] - a.z, sWf[2 * F + 4 * i + 2], acc);
        acc = fmaf(sv[4 * i + 3] - a.w, sWf[2 * F + 4 * i + 3], acc);
    }
    float sp = acc + bf;
    return (sp > 0.f) ? 1.f : (sp < 0.f ? -1.f : 0.f);
}

// ---------------------------------------------------------------------------
// K2 fused: blocks [0,nbw): node W_w path. blocks [nbw,..): edge path —
// XCD-sharded count (L2-local workgroup-scope atomic) + DECOUPLED stores:
// slot_src written as soon as the atomic returns (independent of sign);
// sgn8 byte written when the u/v-gather sign chain resolves. The two
// long-latency chains overlap instead of serializing.
// ---------------------------------------------------------------------------
__global__ __launch_bounds__(256) void ww_count_scatter_kernel(
    const float* __restrict__ h,
    const float* __restrict__ W_w, const float* __restrict__ b_w,
    const float* __restrict__ W_a,
    __half* __restrict__ hp,
    float* __restrict__ a_src, float* __restrict__ a_dst,
    const int* __restrict__ src_idx, const int* __restrict__ dst_idx,
    const float* __restrict__ u_arr, const float* __restrict__ v_arr,
    const float* __restrict__ tfeat, const float* __restrict__ W_f,
    const float* __restrict__ b_f,
    unsigned* __restrict__ cnt, unsigned* __restrict__ slot_src,
    unsigned char* __restrict__ sgn8,
    unsigned* __restrict__ of_list, unsigned* __restrict__ of_cnt,
    int N, int E, int nbw, unsigned of_cap)
{
    __shared__ float sWT[F * F];   // W_w blocks: weights; edge blocks: sWf[0,192)
    __shared__ float sb[F];
    __shared__ float sWa[32];

    int tid = threadIdx.x;

    if (blockIdx.x < nbw) {
        // ---- node W_w path ----
        for (int i = tid; i < F * F; i += 256) {
            int k = i >> 6, j = i & 63;
            sWT[j * F + k] = W_w[i];
        }
        if (tid < F) sb[tid] = b_w[tid];
        if (tid < 32) sWa[tid] = W_a[tid];
        __syncthreads();

        int n = blockIdx.x * 256 + tid;
        if (n >= N) return;

        float4 hv[16];
        const float4* h4 = reinterpret_cast<const float4*>(h + (size_t)n * F);
#pragma unroll
        for (int i = 0; i < 16; i++) hv[i] = h4[i];

        __half2* prow = reinterpret_cast<__half2*>(hp + (size_t)n * F);
#pragma unroll
        for (int qh = 0; qh < 4; qh++) {
            float asq = 0.f, adq = 0.f;
            float pprev = 0.f;
#pragma unroll 4
            for (int jj = 0; jj < 16; jj++) {
                int j = qh * 16 + jj;
                const float4* row = reinterpret_cast<const float4*>(&sWT[j * F]);
                float p = 0.f;
#pragma unroll
                for (int kk = 0; kk < 16; kk++) {
                    float4 w = row[kk];
                    float4 x = hv[kk];
                    p = fmaf(x.x, w.x, p);
                    p = fmaf(x.y, w.y, p);
                    p = fmaf(x.z, w.z, p);
                    p = fmaf(x.w, w.w, p);
                }
                p = p + sb[j];
                asq = fmaf(p, sWa[jj], asq);
                adq = fmaf(p, sWa[16 + jj], adq);
                if ((jj & 1) == 0) pprev = p;
                else prow[j >> 1] = __floats2half2_rn(pprev, p);
            }
            a_src[n * HEADS + qh] = asq;
            a_dst[n * HEADS + qh] = adq;
        }
        return;
    }

    // ---- edge path ----
    float* sWf = sWT;   // reuse first 192 floats
    if (tid < 3 * F) sWf[tid] = W_f[tid];
    __syncthreads();

    unsigned xcc;
    asm volatile("s_getreg_b32 %0, hwreg(HW_REG_XCC_ID)" : "=s"(xcc));
    xcc &= (SHARDS - 1);

    float bf = b_f[0];
    int eb = blockIdx.x - nbw;
    int e0 = eb * 512 + tid;
    int e1 = e0 + 256;
    bool ok0 = e0 < E, ok1 = e1 < E;

    int s0 = 0, d0 = 0, s1 = 0, d1 = 0;
    if (ok0) { s0 = src_idx[e0]; d0 = dst_idx[e0]; }
    if (ok1) { s1 = src_idx[e1]; d1 = dst_idx[e1]; }

    // issue u/v gathers and atomics up front (independent chains)
    float us0 = ok0 ? u_arr[s0] : 0.f, vd0 = ok0 ? v_arr[d0] : 0.f;
    float us1 = ok1 ? u_arr[s1] : 0.f, vd1 = ok1 ? v_arr[d1] : 0.f;
    unsigned p0 = ok0 ? __hip_atomic_fetch_add(&cnt[(size_t)xcc * N + d0], 1u,
                          __ATOMIC_RELAXED, __HIP_MEMORY_SCOPE_WORKGROUP) : 0u;
    unsigned p1 = ok1 ? __hip_atomic_fetch_add(&cnt[(size_t)xcc * N + d1], 1u,
                          __ATOMIC_RELAXED, __HIP_MEMORY_SCOPE_WORKGROUP) : 0u;

    // src stores depend ONLY on the atomic return -> issue immediately
    bool inl0 = ok0 && (p0 < (unsigned)CAPS);
    bool inl1 = ok1 && (p1 < (unsigned)CAPS);
    size_t idx0 = ((size_t)xcc * N + d0) * CAPS + p0;
    size_t idx1 = ((size_t)xcc * N + d1) * CAPS + p1;
    if (inl0) slot_src[idx0] = (unsigned)s0;
    if (inl1) slot_src[idx1] = (unsigned)s1;

    // sign chain resolves in parallel with the stores above
    float m0 = us0 + vd0 + bf;
    float m1 = us1 + vd1 + bf;
    float sg0 = (fabsf(m0) >= 1e-4f) ? ((m0 > 0.f) ? 1.f : -1.f)
              : (ok0 ? tier2_sign(tfeat, sWf, s0, d0, bf) : 0.f);
    float sg1 = (fabsf(m1) >= 1e-4f) ? ((m1 > 0.f) ? 1.f : -1.f)
              : (ok1 ? tier2_sign(tfeat, sWf, s1, d1, bf) : 0.f);
    unsigned c0 = (sg0 > 0.f) ? 0u : (sg0 < 0.f ? 1u : 2u);
    unsigned c1 = (sg1 > 0.f) ? 0u : (sg1 < 0.f ? 1u : 2u);

    if (inl0) sgn8[idx0] = (unsigned char)c0;
    else if (ok0) {
        unsigned oi = atomicAdd(of_cnt, 1u);
        if (oi < of_cap) { of_list[2 * oi] = (unsigned)d0; of_list[2 * oi + 1] = (unsigned)s0 | (c0 << 30); }
    }
    if (inl1) sgn8[idx1] = (unsigned char)c1;
    else if (ok1) {
        unsigned oi = atomicAdd(of_cnt, 1u);
        if (oi < of_cap) { of_list[2 * oi] = (unsigned)d1; of_list[2 * oi + 1] = (unsigned)s1 | (c1 << 30); }
    }
}

// ---------------------------------------------------------------------------
// K3: one wave per dst (r13 structure). Read 8 shard counts, prefix-map lanes
// to (shard,pos); Phase A: slot_src + sgn8 per lane -> 4 signed weights in
// LDS + esum; butterfly. Phase B: 8-way ILP LDS-fed fp16 hp gather; one store.
// Slow path (deg>64 or shard>16 — statistically unreachable).
// ---------------------------------------------------------------------------
__global__ __launch_bounds__(256) void dst_gather_kernel(
    const unsigned* __restrict__ cnt,
    const unsigned* __restrict__ slot_src, const unsigned char* __restrict__ sgn8,
    const unsigned* __restrict__ of_list, const unsigned* __restrict__ of_cnt,
    const float* __restrict__ a_src, const float* __restrict__ a_dst,
    const float* __restrict__ b_a,
    const __half* __restrict__ hp,
    float* __restrict__ out, int N, unsigned of_cap)
{
    __shared__ float sw[4][MAXDEG * 4];     // [wave][slot*4+head] = sgn*ex
    __shared__ unsigned ssrc[4][MAXDEG];    // [wave][slot] = src index

    int tid = threadIdx.x;
    int wslot = tid >> 6;
    int lane = tid & 63;
    int q = lane >> 4;
    int d = (blockIdx.x * 256 + tid) >> 6;
    bool valid = d < N;

    float ba = b_a[0];
    float4 ad4 = make_float4(0.f, 0.f, 0.f, 0.f);
    unsigned csh[SHARDS], pre[SHARDS];
    unsigned deg = 0;
    bool ofl = false;
    if (valid) {
        ad4 = *reinterpret_cast<const float4*>(a_dst + (size_t)d * HEADS);
#pragma unroll
        for (int x = 0; x < SHARDS; x++) {
            unsigned c = cnt[(size_t)x * N + d];
            csh[x] = c; pre[x] = deg; deg += c;
            if (c > (unsigned)CAPS) ofl = true;
        }
    }
    float adq = (q == 0) ? ad4.x : (q == 1) ? ad4.y : (q == 2) ? ad4.z : ad4.w;
    bool fast = valid && (deg <= (unsigned)MAXDEG) && !ofl;

    // Phase A
    float4 p = make_float4(0.f, 0.f, 0.f, 0.f);
    if (fast && lane < (int)deg) {
        int shard = 0; unsigned pos = 0;
#pragma unroll
        for (int x = 0; x < SHARDS; x++)
            if ((unsigned)lane >= pre[x] && (unsigned)lane < pre[x] + csh[x]) {
                shard = x; pos = (unsigned)lane - pre[x];
            }
        size_t idx = ((size_t)shard * N + d) * CAPS + pos;
        unsigned s = slot_src[idx];
        unsigned c = sgn8[idx];
        float sgn = (c == 0u) ? 1.f : (c == 1u ? -1.f : 0.f);
        float4 as4 = *reinterpret_cast<const float4*>(a_src + (size_t)s * HEADS);
        float ap0 = fmaf(sgn, as4.x, ad4.x) + ba;
        float ap1 = fmaf(sgn, as4.y, ad4.y) + ba;
        float ap2 = fmaf(sgn, as4.z, ad4.z) + ba;
        float ap3 = fmaf(sgn, as4.w, ad4.w) + ba;
        float e0 = expf(ap0 > 0.f ? ap0 : 0.01f * ap0);
        float e1 = expf(ap1 > 0.f ? ap1 : 0.01f * ap1);
        float e2 = expf(ap2 > 0.f ? ap2 : 0.01f * ap2);
        float e3 = expf(ap3 > 0.f ? ap3 : 0.01f * ap3);
        p = make_float4(e0, e1, e2, e3);
        *reinterpret_cast<float4*>(&sw[wslot][lane * 4]) =
            make_float4(sgn * e0, sgn * e1, sgn * e2, sgn * e3);
        ssrc[wslot][lane] = s;
    }
    if (valid && !fast) {
        for (int x = 0; x < SHARDS; x++) {
            unsigned cc = min(csh[x], (unsigned)CAPS);
            for (unsigned i = lane; i < cc; i += 64) {
                size_t idx = ((size_t)x * N + d) * CAPS + i;
                unsigned s = slot_src[idx];
                unsigned c = sgn8[idx];
                float sgn = (c == 0u) ? 1.f : (c == 1u ? -1.f : 0.f);
                float4 as4 = *reinterpret_cast<const float4*>(a_src + (size_t)s * HEADS);
                float ap0 = fmaf(sgn, as4.x, ad4.x) + ba;
                float ap1 = fmaf(sgn, as4.y, ad4.y) + ba;
                float ap2 = fmaf(sgn, as4.z, ad4.z) + ba;
                float ap3 = fmaf(sgn, as4.w, ad4.w) + ba;
                p.x += expf(ap0 > 0.f ? ap0 : 0.01f * ap0);
                p.y += expf(ap1 > 0.f ? ap1 : 0.01f * ap1);
                p.z += expf(ap2 > 0.f ? ap2 : 0.01f * ap2);
                p.w += expf(ap3 > 0.f ? ap3 : 0.01f * ap3);
            }
        }
        unsigned on = min(*of_cnt, of_cap);
        for (unsigned i = lane; i < on; i += 64) {
            if (of_list[2 * i] == (unsigned)d) {
                unsigned sp = of_list[2 * i + 1];
                unsigned s = sp & 0x3FFFFFFFu;
                unsigned c = sp >> 30;
                float sgn = (c == 0u) ? 1.f : (c == 1u ? -1.f : 0.f);
                float4 as4 = *reinterpret_cast<const float4*>(a_src + (size_t)s * HEADS);
                float ap0 = fmaf(sgn, as4.x, ad4.x) + ba;
                float ap1 = fmaf(sgn, as4.y, ad4.y) + ba;
                float ap2 = fmaf(sgn, as4.z, ad4.z) + ba;
                float ap3 = fmaf(sgn, as4.w, ad4.w) + ba;
                p.x += expf(ap0 > 0.f ? ap0 : 0.01f * ap0);
                p.y += expf(ap1 > 0.f ? ap1 : 0.01f * ap1);
                p.z += expf(ap2 > 0.f ? ap2 : 0.01f * ap2);
                p.w += expf(ap3 > 0.f ? ap3 : 0.01f * ap3);
            }
        }
    }
    __syncthreads();

#pragma unroll
    for (int off = 32; off >= 1; off >>= 1) {
        p.x += __shfl_xor(p.x, off);
        p.y += __shfl_xor(p.y, off);
        p.z += __shfl_xor(p.z, off);
        p.w += __shfl_xor(p.w, off);
    }
    if (!valid) return;

    float esq = (q == 0) ? p.x : (q == 1) ? p.y : (q == 2) ? p.z : p.w;
    float rinv = (deg > 0) ? (1.0f / esq) : 0.f;

    float a0 = 0.f, a1 = 0.f, a2 = 0.f, a3 = 0.f;
    if (fast) {
        const float* swb = &sw[wslot][0];
        const unsigned* ssb = &ssrc[wslot][0];
        unsigned t0 = 0;
        for (; t0 + 8 <= deg; t0 += 8) {
            float w0 = swb[(t0 + 0) * 4 + q], w1 = swb[(t0 + 1) * 4 + q];
            float w2 = swb[(t0 + 2) * 4 + q], w3 = swb[(t0 + 3) * 4 + q];
            float w4 = swb[(t0 + 4) * 4 + q], w5 = swb[(t0 + 5) * 4 + q];
            float w6 = swb[(t0 + 6) * 4 + q], w7 = swb[(t0 + 7) * 4 + q];
            unsigned s0 = ssb[t0 + 0], s1 = ssb[t0 + 1];
            unsigned s2 = ssb[t0 + 2], s3 = ssb[t0 + 3];
            unsigned s4 = ssb[t0 + 4], s5 = ssb[t0 + 5];
            unsigned s6 = ssb[t0 + 6], s7 = ssb[t0 + 7];
            float h0 = __half2float(hp[((size_t)s0 << 6) | (unsigned)lane]);
            float h1 = __half2float(hp[((size_t)s1 << 6) | (unsigned)lane]);
            float h2 = __half2float(hp[((size_t)s2 << 6) | (unsigned)lane]);
            float h3 = __half2float(hp[((size_t)s3 << 6) | (unsigned)lane]);
            float h4 = __half2float(hp[((size_t)s4 << 6) | (unsigned)lane]);
            float h5 = __half2float(hp[((size_t)s5 << 6) | (unsigned)lane]);
            float h6 = __half2float(hp[((size_t)s6 << 6) | (unsigned)lane]);
            float h7 = __half2float(hp[((size_t)s7 << 6) | (unsigned)lane]);
            a0 = fmaf(w0, h0, a0); a1 = fmaf(w1, h1, a1);
            a2 = fmaf(w2, h2, a2); a3 = fmaf(w3, h3, a3);
            a0 = fmaf(w4, h4, a0); a1 = fmaf(w5, h5, a1);
            a2 = fmaf(w6, h6, a2); a3 = fmaf(w7, h7, a3);
        }
        for (; t0 < deg; t0++) {
            float w = swb[t0 * 4 + q];
            unsigned s = ssb[t0];
            a0 = fmaf(w, __half2float(hp[((size_t)s << 6) | (unsigned)lane]), a0);
        }
    } else {
        for (int x = 0; x < SHARDS; x++) {
            unsigned cc = min(csh[x], (unsigned)CAPS);
            for (unsigned i = 0; i < cc; i++) {
                size_t idx = ((size_t)x * N + d) * CAPS + i;
                unsigned s = slot_src[idx];
                unsigned c = sgn8[idx];
                float g = (c == 0u) ? 1.f : (c == 1u ? -1.f : 0.f);
                float asv = a_src[s * HEADS + q];
                float ap = fmaf(g, asv, adq) + ba;
                float ev = expf(ap > 0.f ? ap : 0.01f * ap);
                a0 = fmaf(ev * g, __half2float(hp[((size_t)s << 6) | (unsigned)lane]), a0);
            }
        }
        unsigned on = min(*of_cnt, of_cap);
        for (unsigned i = 0; i < on; i++) {
            if (of_list[2 * i] == (unsigned)d) {
                unsigned sp = of_list[2 * i + 1];
                unsigned s = sp & 0x3FFFFFFFu;
                unsigned c = sp >> 30;
                float g = (c == 0u) ? 1.f : (c == 1u ? -1.f : 0.f);
                float asv = a_src[s * HEADS + q];
                float ap = fmaf(g, asv, adq) + ba;
                float ev = expf(ap > 0.f ? ap : 0.01f * ap);
                a0 = fmaf(ev * g, __half2float(hp[((size_t)s << 6) | (unsigned)lane]), a0);
            }
        }
    }
    out[((size_t)d << 6) | (unsigned)lane] = ((a0 + a1) + (a2 + a3)) * rinv;
}

// ---------------------------------------------------------------------------
extern "C" void kernel_launch(void* const* d_in, const int* in_sizes, int n_in,
                              void* d_out, int out_size, void* d_ws, size_t ws_size,
                              hipStream_t stream)
{
    const float* h       = (const float*)d_in[0];
    const int*   src_idx = (const int*)d_in[1];
    const int*   dst_idx = (const int*)d_in[2];
    const float* W_w     = (const float*)d_in[3];
    const float* b_w     = (const float*)d_in[4];
    const float* W_a     = (const float*)d_in[5];
    const float* b_a     = (const float*)d_in[6];
    const float* W_d     = (const float*)d_in[7];
    const float* b_d     = (const float*)d_in[8];
    const float* W_f     = (const float*)d_in[9];
    const float* b_f     = (const float*)d_in[10];

    int N = in_sizes[0] / F;
    int E = in_sizes[1];
    int nb = (N + 255) / 256;
    int neb = (E + 511) / 512;
    unsigned of_cap = (unsigned)(E / 8);

    char* ws = (char*)d_ws;
    float*         tfeat  = (float*)ws;         ws += (size_t)N * F * 4;             // 12.8MB
    __half*        hp     = (__half*)ws;        ws += (size_t)N * F * 2;             // 6.4MB
    float*         u_arr  = (float*)ws;         ws += (size_t)N * 4;                 // 0.2MB
    float*         v_arr  = (float*)ws;         ws += (size_t)N * 4;                 // 0.2MB
    float*         a_src  = (float*)ws;         ws += (size_t)N * HEADS * 4;         // 0.8MB
    float*         a_dst  = (float*)ws;         ws += (size_t)N * HEADS * 4;         // 0.8MB
    unsigned*      cnt    = (unsigned*)ws;      ws += (size_t)SHARDS * N * 4;        // 1.6MB
    unsigned*      of_cnt = (unsigned*)ws;      ws += 64;                            // 64B
    unsigned*      slot_s = (unsigned*)ws;      ws += (size_t)SHARDS * N * CAPS * 4; // 25.6MB
    unsigned char* sgn8   = (unsigned char*)ws; ws += (size_t)SHARDS * N * CAPS;     // 6.4MB
    unsigned*      of_list= (unsigned*)ws;      ws += (size_t)of_cap * 8;            // 1MB

    float* out = (float*)d_out;

    node_wd_kernel<<<nb, 256, 0, stream>>>(
        h, W_d, b_d, W_f, tfeat, u_arr, v_arr, cnt, of_cnt, N);

    ww_count_scatter_kernel<<<nb + neb, 256, 0, stream>>>(
        h, W_w, b_w, W_a, hp, a_src, a_dst,
        src_idx, dst_idx, u_arr, v_arr, tfeat, W_f, b_f,
        cnt, slot_s, sgn8, of_list, of_cnt, N, E, nb, of_cap);

    dst_gather_kernel<<<(N * 64 + 255) / 256, 256, 0, stream>>>(
        cnt, slot_s, sgn8, of_list, of_cnt, a_src, a_dst, b_a, hp, out, N, of_cap);
}

// Round 19
// 123.083 us; speedup vs baseline: 1.5418x; 1.0402x over previous
//
#include <hip/hip_runtime.h>
#include <hip/hip_fp16.h>

constexpr int F  = 64;   // IN_FEATS == ATT_HEADS*H_FEATS
constexpr int HEADS = 4;
constexpr int SHARDS = 8;    // one slot/counter shard per XCD
constexpr int CAPS = 8;      // per-shard per-dst slots (2.2MB/XCD -> L2-resident)
constexpr int OCAP = 56;     // per-dst global overflow slots (fast-path consumed)
constexpr int MAXDEG = 64;   // per-wave LDS slots in gather

// ---------------------------------------------------------------------------
// K1 (per node): W_d path. tfeat fp32 (BLAS-order), u/v fp32;
// zero cnt shards + ocnt + of_cnt.
// ---------------------------------------------------------------------------
__global__ __launch_bounds__(256) void node_wd_kernel(
    const float* __restrict__ h,
    const float* __restrict__ W_d, const float* __restrict__ b_d,
    const float* __restrict__ W_f,
    float* __restrict__ tfeat,
    float* __restrict__ u_arr, float* __restrict__ v_arr,
    unsigned* __restrict__ cnt, unsigned* __restrict__ ocnt,
    unsigned* __restrict__ of_cnt, int N)
{
    __shared__ float sWT[F * F];     // [j][k] transposed
    __shared__ float sb[F];
    __shared__ double swfA[F], swfB[F];

    int tid = threadIdx.x;
    for (int i = tid; i < F * F; i += 256) {
        int k = i >> 6, j = i & 63;
        sWT[j * F + k] = W_d[i];
    }
    if (tid < F) {
        sb[tid] = b_d[tid];
        swfA[tid] = (double)W_f[tid] + (double)W_f[2 * F + tid];
        swfB[tid] = (double)W_f[F + tid] - (double)W_f[2 * F + tid];
    }
    if (blockIdx.x == 0 && tid == 0) *of_cnt = 0;
    __syncthreads();

    int n = blockIdx.x * 256 + tid;
    if (n >= N) return;

#pragma unroll
    for (int x = 0; x < SHARDS; x++) cnt[(size_t)x * N + n] = 0;
    ocnt[n] = 0;

    float4 hv[16];
    const float4* h4 = reinterpret_cast<const float4*>(h + (size_t)n * F);
#pragma unroll
    for (int i = 0; i < 16; i++) hv[i] = h4[i];

    double u = 0.0, v = 0.0;
    float4 tq;
    float4* trow = reinterpret_cast<float4*>(tfeat + (size_t)n * F);
#pragma unroll 4
    for (int j = 0; j < F; j++) {
        const float4* row = reinterpret_cast<const float4*>(&sWT[j * F]);
        float t = 0.f;
#pragma unroll
        for (int kk = 0; kk < 16; kk++) {
            float4 w = row[kk];
            float4 x = hv[kk];
            t = fmaf(x.x, w.x, t);
            t = fmaf(x.y, w.y, t);
            t = fmaf(x.z, w.z, t);
            t = fmaf(x.w, w.w, t);
        }
        t = t + sb[j];
        u = fma((double)t, swfA[j], u);
        v = fma((double)t, swfB[j], v);
        if ((j & 3) == 0) tq.x = t;
        else if ((j & 3) == 1) tq.y = t;
        else if ((j & 3) == 2) tq.z = t;
        else { tq.w = t; trow[j >> 2] = tq; }
    }
    u_arr[n] = (float)u;
    v_arr[n] = (float)v;
}

// ---------------------------------------------------------------------------
// Tier-2 sign fallback: literal fp32 192-term sequential FMA in the
// reference's e_feat section order (rare: |fp32 margin| < 1e-4).
// ---------------------------------------------------------------------------
__device__ __noinline__ float tier2_sign(
    const float* __restrict__ tfeat, const float* __restrict__ sWf,
    int s, int d, float bf)
{
    const float4* ts = reinterpret_cast<const float4*>(tfeat + (size_t)s * F);
    const float4* td = reinterpret_cast<const float4*>(tfeat + (size_t)d * F);
    float sv[F];
#pragma unroll
    for (int i = 0; i < 16; i++) {
        float4 a = ts[i];
        sv[4 * i + 0] = a.x; sv[4 * i + 1] = a.y;
        sv[4 * i + 2] = a.z; sv[4 * i + 3] = a.w;
    }
    float acc = 0.f;
#pragma unroll
    for (int j = 0; j < F; j++) acc = fmaf(sv[j], sWf[j], acc);
#pragma unroll
    for (int i = 0; i < 16; i++) {
        float4 a = td[i];
        acc = fmaf(a.x, sWf[F + 4 * i + 0], acc);
        acc = fmaf(a.y, sWf[F + 4 * i + 1], acc);
        acc = fmaf(a.z, sWf[F + 4 * i + 2], acc);
        acc = fmaf(a.w, sWf[F + 4 * i + 3], acc);
    }
#pragma unroll
    for (int i = 0; i < 16; i++) {
        float4 a = td[i];
        acc = fmaf(sv[4 * i + 0] - a.x, sWf[2 * F + 4 * i + 0], acc);
        acc = fmaf(sv[4 * i + 1] - a.y, sWf[2 * F + 4 * i + 1], acc);
        acc = fmaf(sv[4 * i + 2] - a.z, sWf[2 * F + 4 * i + 2], acc);
        acc = fmaf(sv[4 * i + 3] - a.w, sWf[2 * F + 4 * i + 3], acc);
    }
    float sp = acc + bf;
    return (sp > 0.f) ? 1.f : (sp < 0.f ? -1.f : 0.f);
}

// ---------------------------------------------------------------------------
// K2 fused: blocks [0,nbw): node W_w path. blocks [nbw,..): edge path —
// XCD-sharded count (L2-local workgroup-scope atomic, CAPS=8 -> 2.2MB/XCD
// working set stays L2-resident) + decoupled slot_src/sgn8 stores.
// Shard overflow (~100 edges): per-dst global ovf via device-scope ocnt.
// ---------------------------------------------------------------------------
__global__ __launch_bounds__(256) void ww_count_scatter_kernel(
    const float* __restrict__ h,
    const float* __restrict__ W_w, const float* __restrict__ b_w,
    const float* __restrict__ W_a,
    __half* __restrict__ hp,
    float* __restrict__ a_src, float* __restrict__ a_dst,
    const int* __restrict__ src_idx, const int* __restrict__ dst_idx,
    const float* __restrict__ u_arr, const float* __restrict__ v_arr,
    const float* __restrict__ tfeat, const float* __restrict__ W_f,
    const float* __restrict__ b_f,
    unsigned* __restrict__ cnt, unsigned* __restrict__ slot_src,
    unsigned char* __restrict__ sgn8,
    unsigned* __restrict__ ocnt, unsigned* __restrict__ ovf,
    unsigned* __restrict__ of_list, unsigned* __restrict__ of_cnt,
    int N, int E, int nbw, unsigned of_cap)
{
    __shared__ float sWT[F * F];   // W_w blocks: weights; edge blocks: sWf[0,192)
    __shared__ float sb[F];
    __shared__ float sWa[32];

    int tid = threadIdx.x;

    if (blockIdx.x < nbw) {
        // ---- node W_w path ----
        for (int i = tid; i < F * F; i += 256) {
            int k = i >> 6, j = i & 63;
            sWT[j * F + k] = W_w[i];
        }
        if (tid < F) sb[tid] = b_w[tid];
        if (tid < 32) sWa[tid] = W_a[tid];
        __syncthreads();

        int n = blockIdx.x * 256 + tid;
        if (n >= N) return;

        float4 hv[16];
        const float4* h4 = reinterpret_cast<const float4*>(h + (size_t)n * F);
#pragma unroll
        for (int i = 0; i < 16; i++) hv[i] = h4[i];

        __half2* prow = reinterpret_cast<__half2*>(hp + (size_t)n * F);
#pragma unroll
        for (int qh = 0; qh < 4; qh++) {
            float asq = 0.f, adq = 0.f;
            float pprev = 0.f;
#pragma unroll 4
            for (int jj = 0; jj < 16; jj++) {
                int j = qh * 16 + jj;
                const float4* row = reinterpret_cast<const float4*>(&sWT[j * F]);
                float p = 0.f;
#pragma unroll
                for (int kk = 0; kk < 16; kk++) {
                    float4 w = row[kk];
                    float4 x = hv[kk];
                    p = fmaf(x.x, w.x, p);
                    p = fmaf(x.y, w.y, p);
                    p = fmaf(x.z, w.z, p);
                    p = fmaf(x.w, w.w, p);
                }
                p = p + sb[j];
                asq = fmaf(p, sWa[jj], asq);
                adq = fmaf(p, sWa[16 + jj], adq);
                if ((jj & 1) == 0) pprev = p;
                else prow[j >> 1] = __floats2half2_rn(pprev, p);
            }
            a_src[n * HEADS + qh] = asq;
            a_dst[n * HEADS + qh] = adq;
        }
        return;
    }

    // ---- edge path ----
    float* sWf = sWT;   // reuse first 192 floats
    if (tid < 3 * F) sWf[tid] = W_f[tid];
    __syncthreads();

    unsigned xcc;
    asm volatile("s_getreg_b32 %0, hwreg(HW_REG_XCC_ID)" : "=s"(xcc));
    xcc &= (SHARDS - 1);

    float bf = b_f[0];
    int eb = blockIdx.x - nbw;
    int e0 = eb * 512 + tid;
    int e1 = e0 + 256;
    bool ok0 = e0 < E, ok1 = e1 < E;

    int s0 = 0, d0 = 0, s1 = 0, d1 = 0;
    if (ok0) { s0 = src_idx[e0]; d0 = dst_idx[e0]; }
    if (ok1) { s1 = src_idx[e1]; d1 = dst_idx[e1]; }

    // issue u/v gathers and atomics up front (independent chains)
    float us0 = ok0 ? u_arr[s0] : 0.f, vd0 = ok0 ? v_arr[d0] : 0.f;
    float us1 = ok1 ? u_arr[s1] : 0.f, vd1 = ok1 ? v_arr[d1] : 0.f;
    unsigned p0 = ok0 ? __hip_atomic_fetch_add(&cnt[(size_t)xcc * N + d0], 1u,
                          __ATOMIC_RELAXED, __HIP_MEMORY_SCOPE_WORKGROUP) : 0u;
    unsigned p1 = ok1 ? __hip_atomic_fetch_add(&cnt[(size_t)xcc * N + d1], 1u,
                          __ATOMIC_RELAXED, __HIP_MEMORY_SCOPE_WORKGROUP) : 0u;

    // src stores depend ONLY on the atomic return -> issue immediately
    bool inl0 = ok0 && (p0 < (unsigned)CAPS);
    bool inl1 = ok1 && (p1 < (unsigned)CAPS);
    size_t idx0 = ((size_t)xcc * N + d0) * CAPS + p0;
    size_t idx1 = ((size_t)xcc * N + d1) * CAPS + p1;
    if (inl0) slot_src[idx0] = (unsigned)s0;
    if (inl1) slot_src[idx1] = (unsigned)s1;

    // sign chain resolves in parallel
    float m0 = us0 + vd0 + bf;
    float m1 = us1 + vd1 + bf;
    float sg0 = (fabsf(m0) >= 1e-4f) ? ((m0 > 0.f) ? 1.f : -1.f)
              : (ok0 ? tier2_sign(tfeat, sWf, s0, d0, bf) : 0.f);
    float sg1 = (fabsf(m1) >= 1e-4f) ? ((m1 > 0.f) ? 1.f : -1.f)
              : (ok1 ? tier2_sign(tfeat, sWf, s1, d1, bf) : 0.f);
    unsigned c0 = (sg0 > 0.f) ? 0u : (sg0 < 0.f ? 1u : 2u);
    unsigned c1 = (sg1 > 0.f) ? 0u : (sg1 < 0.f ? 1u : 2u);

    if (inl0) sgn8[idx0] = (unsigned char)c0;
    else if (ok0) {
        unsigned po = atomicAdd(&ocnt[d0], 1u);     // device scope (rare)
        if (po < (unsigned)OCAP) ovf[(size_t)d0 * OCAP + po] = (unsigned)s0 | (c0 << 30);
        else {
            unsigned oi = atomicAdd(of_cnt, 1u);
            if (oi < of_cap) { of_list[2 * oi] = (unsigned)d0; of_list[2 * oi + 1] = (unsigned)s0 | (c0 << 30); }
        }
    }
    if (inl1) sgn8[idx1] = (unsigned char)c1;
    else if (ok1) {
        unsigned po = atomicAdd(&ocnt[d1], 1u);
        if (po < (unsigned)OCAP) ovf[(size_t)d1 * OCAP + po] = (unsigned)s1 | (c1 << 30);
        else {
            unsigned oi = atomicAdd(of_cnt, 1u);
            if (oi < of_cap) { of_list[2 * oi] = (unsigned)d1; of_list[2 * oi + 1] = (unsigned)s1 | (c1 << 30); }
        }
    }
}

// ---------------------------------------------------------------------------
// K3: one wave per dst. Shard entries (capped 8) + per-dst ovf entries are
// BOTH fast-path: lanes 0..degS-1 map to (shard,pos), lanes degS..degT-1
// read ovf[d]. Phase A -> signed weights in LDS + esum; butterfly. Phase B:
// 8-way ILP LDS-fed fp16 hp gather; one store. of_list slow path only if
// ocnt>OCAP or degT>64 (statistically unreachable).
// ---------------------------------------------------------------------------
__global__ __launch_bounds__(256) void dst_gather_kernel(
    const unsigned* __restrict__ cnt,
    const unsigned* __restrict__ slot_src, const unsigned char* __restrict__ sgn8,
    const unsigned* __restrict__ ocnt, const unsigned* __restrict__ ovf,
    const unsigned* __restrict__ of_list, const unsigned* __restrict__ of_cnt,
    const float* __restrict__ a_src, const float* __restrict__ a_dst,
    const float* __restrict__ b_a,
    const __half* __restrict__ hp,
    float* __restrict__ out, int N, unsigned of_cap)
{
    __shared__ float sw[4][MAXDEG * 4];     // [wave][slot*4+head] = sgn*ex
    __shared__ unsigned ssrc[4][MAXDEG];    // [wave][slot] = src index

    int tid = threadIdx.x;
    int wslot = tid >> 6;
    int lane = tid & 63;
    int q = lane >> 4;
    int d = (blockIdx.x * 256 + tid) >> 6;
    bool valid = d < N;

    float ba = b_a[0];
    float4 ad4 = make_float4(0.f, 0.f, 0.f, 0.f);
    unsigned csh[SHARDS], pre[SHARDS];
    unsigned degS = 0, oc = 0, ocr = 0;
    if (valid) {
        ad4 = *reinterpret_cast<const float4*>(a_dst + (size_t)d * HEADS);
#pragma unroll
        for (int x = 0; x < SHARDS; x++) {
            unsigned c = cnt[(size_t)x * N + d];
            csh[x] = min(c, (unsigned)CAPS);
            pre[x] = degS;
            degS += csh[x];
        }
        ocr = ocnt[d];
        oc = min(ocr, (unsigned)OCAP);
    }
    float adq = (q == 0) ? ad4.x : (q == 1) ? ad4.y : (q == 2) ? ad4.z : ad4.w;
    unsigned degT = degS + oc;
    bool fast = valid && (degT <= (unsigned)MAXDEG) && (ocr <= (unsigned)OCAP);

    // Phase A
    float4 p = make_float4(0.f, 0.f, 0.f, 0.f);
    if (fast && lane < (int)degT) {
        unsigned s, c;
        if ((unsigned)lane < degS) {
            int shard = 0; unsigned pos = 0;
#pragma unroll
            for (int x = 0; x < SHARDS; x++)
                if ((unsigned)lane >= pre[x] && (unsigned)lane < pre[x] + csh[x]) {
                    shard = x; pos = (unsigned)lane - pre[x];
                }
            size_t idx = ((size_t)shard * N + d) * CAPS + pos;
            s = slot_src[idx];
            c = sgn8[idx];
        } else {
            unsigned v = ovf[(size_t)d * OCAP + ((unsigned)lane - degS)];
            s = v & 0x3FFFFFFFu;
            c = v >> 30;
        }
        float sgn = (c == 0u) ? 1.f : (c == 1u ? -1.f : 0.f);
        float4 as4 = *reinterpret_cast<const float4*>(a_src + (size_t)s * HEADS);
        float ap0 = fmaf(sgn, as4.x, ad4.x) + ba;
        float ap1 = fmaf(sgn, as4.y, ad4.y) + ba;
        float ap2 = fmaf(sgn, as4.z, ad4.z) + ba;
        float ap3 = fmaf(sgn, as4.w, ad4.w) + ba;
        float e0 = expf(ap0 > 0.f ? ap0 : 0.01f * ap0);
        float e1 = expf(ap1 > 0.f ? ap1 : 0.01f * ap1);
        float e2 = expf(ap2 > 0.f ? ap2 : 0.01f * ap2);
        float e3 = expf(ap3 > 0.f ? ap3 : 0.01f * ap3);
        p = make_float4(e0, e1, e2, e3);
        *reinterpret_cast<float4*>(&sw[wslot][lane * 4]) =
            make_float4(sgn * e0, sgn * e1, sgn * e2, sgn * e3);
        ssrc[wslot][lane] = s;
    }
    if (valid && !fast) {
        // slow path esum: shard slots + ovf + of_list
        for (int x = 0; x < SHARDS; x++) {
            for (unsigned i = lane; i < csh[x]; i += 64) {
                size_t idx = ((size_t)x * N + d) * CAPS + i;
                unsigned s = slot_src[idx];
                unsigned c = sgn8[idx];
                float sgn = (c == 0u) ? 1.f : (c == 1u ? -1.f : 0.f);
                float4 as4 = *reinterpret_cast<const float4*>(a_src + (size_t)s * HEADS);
                float ap0 = fmaf(sgn, as4.x, ad4.x) + ba;
                float ap1 = fmaf(sgn, as4.y, ad4.y) + ba;
                float ap2 = fmaf(sgn, as4.z, ad4.z) + ba;
                float ap3 = fmaf(sgn, as4.w, ad4.w) + ba;
                p.x += expf(ap0 > 0.f ? ap0 : 0.01f * ap0);
                p.y += expf(ap1 > 0.f ? ap1 : 0.01f * ap1);
                p.z += expf(ap2 > 0.f ? ap2 : 0.01f * ap2);
                p.w += expf(ap3 > 0.f ? ap3 : 0.01f * ap3);
            }
        }
        for (unsigned i = lane; i < oc; i += 64) {
            unsigned v = ovf[(size_t)d * OCAP + i];
            unsigned s = v & 0x3FFFFFFFu;
            unsigned c = v >> 30;
            float sgn = (c == 0u) ? 1.f : (c == 1u ? -1.f : 0.f);
            float4 as4 = *reinterpret_cast<const float4*>(a_src + (size_t)s * HEADS);
            float ap0 = fmaf(sgn, as4.x, ad4.x) + ba;
            float ap1 = fmaf(sgn, as4.y, ad4.y) + ba;
            float ap2 = fmaf(sgn, as4.z, ad4.z) + ba;
            float ap3 = fmaf(sgn, as4.w, ad4.w) + ba;
            p.x += expf(ap0 > 0.f ? ap0 : 0.01f * ap0);
            p.y += expf(ap1 > 0.f ? ap1 : 0.01f * ap1);
            p.z += expf(ap2 > 0.f ? ap2 : 0.01f * ap2);
            p.w += expf(ap3 > 0.f ? ap3 : 0.01f * ap3);
        }
        unsigned on = min(*of_cnt, of_cap);
        for (unsigned i = lane; i < on; i += 64) {
            if (of_list[2 * i] == (unsigned)d) {
                unsigned sp = of_list[2 * i + 1];
                unsigned s = sp & 0x3FFFFFFFu;
                unsigned c = sp >> 30;
                float sgn = (c == 0u) ? 1.f : (c == 1u ? -1.f : 0.f);
                float4 as4 = *reinterpret_cast<const float4*>(a_src + (size_t)s * HEADS);
                float ap0 = fmaf(sgn, as4.x, ad4.x) + ba;
                float ap1 = fmaf(sgn, as4.y, ad4.y) + ba;
                float ap2 = fmaf(sgn, as4.z, ad4.z) + ba;
                float ap3 = fmaf(sgn, as4.w, ad4.w) + ba;
                p.x += expf(ap0 > 0.f ? ap0 : 0.01f * ap0);
                p.y += expf(ap1 > 0.f ? ap1 : 0.01f * ap1);
                p.z += expf(ap2 > 0.f ? ap2 : 0.01f * ap2);
                p.w += expf(ap3 > 0.f ? ap3 : 0.01f * ap3);
            }
        }
    }
    __syncthreads();

#pragma unroll
    for (int off = 32; off >= 1; off >>= 1) {
        p.x += __shfl_xor(p.x, off);
        p.y += __shfl_xor(p.y, off);
        p.z += __shfl_xor(p.z, off);
        p.w += __shfl_xor(p.w, off);
    }
    if (!valid) return;

    float esq = (q == 0) ? p.x : (q == 1) ? p.y : (q == 2) ? p.z : p.w;
    float rinv = (esq > 0.f) ? (1.0f / esq) : 0.f;

    float a0 = 0.f, a1 = 0.f, a2 = 0.f, a3 = 0.f;
    if (fast) {
        const float* swb = &sw[wslot][0];
        const unsigned* ssb = &ssrc[wslot][0];
        unsigned t0 = 0;
        for (; t0 + 8 <= degT; t0 += 8) {
            float w0 = swb[(t0 + 0) * 4 + q], w1 = swb[(t0 + 1) * 4 + q];
            float w2 = swb[(t0 + 2) * 4 + q], w3 = swb[(t0 + 3) * 4 + q];
            float w4 = swb[(t0 + 4) * 4 + q], w5 = swb[(t0 + 5) * 4 + q];
            float w6 = swb[(t0 + 6) * 4 + q], w7 = swb[(t0 + 7) * 4 + q];
            unsigned s0 = ssb[t0 + 0], s1 = ssb[t0 + 1];
            unsigned s2 = ssb[t0 + 2], s3 = ssb[t0 + 3];
            unsigned s4 = ssb[t0 + 4], s5 = ssb[t0 + 5];
            unsigned s6 = ssb[t0 + 6], s7 = ssb[t0 + 7];
            float h0 = __half2float(hp[((size_t)s0 << 6) | (unsigned)lane]);
            float h1 = __half2float(hp[((size_t)s1 << 6) | (unsigned)lane]);
            float h2 = __half2float(hp[((size_t)s2 << 6) | (unsigned)lane]);
            float h3 = __half2float(hp[((size_t)s3 << 6) | (unsigned)lane]);
            float h4 = __half2float(hp[((size_t)s4 << 6) | (unsigned)lane]);
            float h5 = __half2float(hp[((size_t)s5 << 6) | (unsigned)lane]);
            float h6 = __half2float(hp[((size_t)s6 << 6) | (unsigned)lane]);
            float h7 = __half2float(hp[((size_t)s7 << 6) | (unsigned)lane]);
            a0 = fmaf(w0, h0, a0); a1 = fmaf(w1, h1, a1);
            a2 = fmaf(w2, h2, a2); a3 = fmaf(w3, h3, a3);
            a0 = fmaf(w4, h4, a0); a1 = fmaf(w5, h5, a1);
            a2 = fmaf(w6, h6, a2); a3 = fmaf(w7, h7, a3);
        }
        for (; t0 < degT; t0++) {
            float w = swb[t0 * 4 + q];
            unsigned s = ssb[t0];
            a0 = fmaf(w, __half2float(hp[((size_t)s << 6) | (unsigned)lane]), a0);
        }
    } else {
        for (int x = 0; x < SHARDS; x++) {
            for (unsigned i = 0; i < csh[x]; i++) {
                size_t idx = ((size_t)x * N + d) * CAPS + i;
                unsigned s = slot_src[idx];
                unsigned c = sgn8[idx];
                float g = (c == 0u) ? 1.f : (c == 1u ? -1.f : 0.f);
                float asv = a_src[s * HEADS + q];
                float ap = fmaf(g, asv, adq) + ba;
                float ev = expf(ap > 0.f ? ap : 0.01f * ap);
                a0 = fmaf(ev * g, __half2float(hp[((size_t)s << 6) | (unsigned)lane]), a0);
            }
        }
        for (unsigned i = 0; i < oc; i++) {
            unsigned v = ovf[(size_t)d * OCAP + i];
            unsigned s = v & 0x3FFFFFFFu;
            unsigned c = v >> 30;
            float g = (c == 0u) ? 1.f : (c == 1u ? -1.f : 0.f);
            float asv = a_src[s * HEADS + q];
            float ap = fmaf(g, asv, adq) + ba;
            float ev = expf(ap > 0.f ? ap : 0.01f * ap);
            a0 = fmaf(ev * g, __half2float(hp[((size_t)s << 6) | (unsigned)lane]), a0);
        }
        unsigned on = min(*of_cnt, of_cap);
        for (unsigned i = 0; i < on; i++) {
            if (of_list[2 * i] == (unsigned)d) {
                unsigned sp = of_list[2 * i + 1];
                unsigned s = sp & 0x3FFFFFFFu;
                unsigned c = sp >> 30;
                float g = (c == 0u) ? 1.f : (c == 1u ? -1.f : 0.f);
                float asv = a_src[s * HEADS + q];
                float ap = fmaf(g, asv, adq) + ba;
                float ev = expf(ap > 0.f ? ap : 0.01f * ap);
                a0 = fmaf(ev * g, __half2float(hp[((size_t)s << 6) | (unsigned)lane]), a0);
            }
        }
    }
    out[((size_t)d << 6) | (unsigned)lane] = ((a0 + a1) + (a2 + a3)) * rinv;
}

// ---------------------------------------------------------------------------
extern "C" void kernel_launch(void* const* d_in, const int* in_sizes, int n_in,
                              void* d_out, int out_size, void* d_ws, size_t ws_size,
                              hipStream_t stream)
{
    const float* h       = (const float*)d_in[0];
    const int*   src_idx = (const int*)d_in[1];
    const int*   dst_idx = (const int*)d_in[2];
    const float* W_w     = (const float*)d_in[3];
    const float* b_w     = (const float*)d_in[4];
    const float* W_a     = (const float*)d_in[5];
    const float* b_a     = (const float*)d_in[6];
    const float* W_d     = (const float*)d_in[7];
    const float* b_d     = (const float*)d_in[8];
    const float* W_f     = (const float*)d_in[9];
    const float* b_f     = (const float*)d_in[10];

    int N = in_sizes[0] / F;
    int E = in_sizes[1];
    int nb = (N + 255) / 256;
    int neb = (E + 511) / 512;
    unsigned of_cap = (unsigned)(E / 16);

    char* ws = (char*)d_ws;
    float*         tfeat  = (float*)ws;         ws += (size_t)N * F * 4;             // 12.8MB
    __half*        hp     = (__half*)ws;        ws += (size_t)N * F * 2;             // 6.4MB
    float*         u_arr  = (float*)ws;         ws += (size_t)N * 4;                 // 0.2MB
    float*         v_arr  = (float*)ws;         ws += (size_t)N * 4;                 // 0.2MB
    float*         a_src  = (float*)ws;         ws += (size_t)N * HEADS * 4;         // 0.8MB
    float*         a_dst  = (float*)ws;         ws += (size_t)N * HEADS * 4;         // 0.8MB
    unsigned*      cnt    = (unsigned*)ws;      ws += (size_t)SHARDS * N * 4;        // 1.6MB
    unsigned*      ocnt   = (unsigned*)ws;      ws += (size_t)N * 4;                 // 0.2MB
    unsigned*      of_cnt = (unsigned*)ws;      ws += 64;                            // 64B
    unsigned*      slot_s = (unsigned*)ws;      ws += (size_t)SHARDS * N * CAPS * 4; // 12.8MB
    unsigned char* sgn8   = (unsigned char*)ws; ws += (size_t)SHARDS * N * CAPS;     // 3.2MB
    unsigned*      ovf    = (unsigned*)ws;      ws += (size_t)N * OCAP * 4;          // 11.2MB
    unsigned*      of_list= (unsigned*)ws;      ws += (size_t)of_cap * 8;            // 0.5MB

    float* out = (float*)d_out;

    node_wd_kernel<<<nb, 256, 0, stream>>>(
        h, W_d, b_d, W_f, tfeat, u_arr, v_arr, cnt, ocnt, of_cnt, N);

    ww_count_scatter_kernel<<<nb + neb, 256, 0, stream>>>(
        h, W_w, b_w, W_a, hp, a_src, a_dst,
        src_idx, dst_idx, u_arr, v_arr, tfeat, W_f, b_f,
        cnt, slot_s, sgn8, ocnt, ovf, of_list, of_cnt, N, E, nb, of_cap);

    dst_gather_kernel<<<(N * 64 + 255) / 256, 256, 0, stream>>>(
        cnt, slot_s, sgn8, ocnt, ovf, of_list, of_cnt,
        a_src, a_dst, b_a, hp, out, N, of_cap);
}